// Round 3
// baseline (762.327 us; speedup 1.0000x reference)
//
#include <hip/hip_runtime.h>

typedef unsigned int uint;
typedef unsigned short ushort;
typedef __attribute__((ext_vector_type(8))) short short8;   // 8 bf16 (4 VGPRs)
typedef __attribute__((ext_vector_type(4))) float f32x4;    // MFMA accumulator

// ---------- bf16 helpers (internal storage only; I/O is fp32) ----------
__device__ __forceinline__ float bflo(uint u) { return __uint_as_float(u << 16); }
__device__ __forceinline__ float bfhi(uint u) { return __uint_as_float(u & 0xffff0000u); }
__device__ __forceinline__ ushort f2bf(float f) {
    uint u = __float_as_uint(f);
    u += 0x7fffu + ((u >> 16) & 1u);   // round-to-nearest-even
    return (ushort)(u >> 16);
}
__device__ __forceinline__ uint pack2(float a, float b) {
    return (uint)f2bf(a) | ((uint)f2bf(b) << 16);
}
__device__ __forceinline__ float sigm(float e) { return 1.0f / (1.0f + __expf(-e)); }

#define ND0 200000
#define ND1 100000
#define INF 128
#define HF  256
#define BCAP 32768   // bucket capacity incl. 16-entry flush padding (worst ~29K)
#define GSTRIDE 16   // gcur padded to 64B/line to avoid same-line atomic serialization
#define NBKT 200     // max 1024-dst buckets (196 for ND0, 98 for ND1)
#define CAP_A 48     // per-bucket LDS staging capacity per round (mean ~21, ~6 sigma)
#define SENT 0xFFFFFFFFu   // pad sentinel; real entries max (400000<<10)|1023 < SENT

// ---------- 1) gate: h[n,f] = feat * sigmoid(emb[cell_id]) ; h bf16 ----------
__global__ __launch_bounds__(256) void gate_k(const float* __restrict__ x,
                                              const float* __restrict__ emb,
                                              ushort* __restrict__ h, int nnodes) {
    int tid  = blockIdx.x * 256 + threadIdx.x;
    int node = tid >> 4, tq = tid & 15;
    if (node >= nnodes) return;
    const float* xr = x + (size_t)node * 129;
    int cell = (int)xr[0];
    int f0 = tq * 8;
    const float* er = emb + cell * INF + f0;
    float4 e0 = *(const float4*)er;
    float4 e1 = *(const float4*)(er + 4);
    float v[8];
    __builtin_memcpy(&v[0], xr + 1 + f0, 16);      // 4B-aligned dwordx4
    __builtin_memcpy(&v[4], xr + 5 + f0, 16);
    uint4 o;
    o.x = pack2(v[0] * sigm(e0.x), v[1] * sigm(e0.y));
    o.y = pack2(v[2] * sigm(e0.z), v[3] * sigm(e0.w));
    o.z = pack2(v[4] * sigm(e1.x), v[5] * sigm(e1.y));
    o.w = pack2(v[6] * sigm(e1.z), v[7] * sigm(e1.w));
    *(uint4*)(h + (size_t)node * INF + f0) = o;
}

// ---------- CSR build ----------
#define SCAN_B 1024
// scans PADDED counts: (cnt+3)&~3 — keeps every CSR row 4-aligned
__global__ __launch_bounds__(256) void scan1_k(const int* __restrict__ in,
                                               int* __restrict__ out,
                                               int* __restrict__ bsum, int n) {
    __shared__ int tmp[256];
    int t = threadIdx.x;
    int base = blockIdx.x * SCAN_B;
    int v[4], s = 0;
#pragma unroll
    for (int q = 0; q < 4; ++q) {
        int idx = base + t * 4 + q;
        v[q] = (idx < n) ? ((in[idx] + 3) & ~3) : 0;
        s += v[q];
    }
    tmp[t] = s; __syncthreads();
    for (int off = 1; off < 256; off <<= 1) {
        int xv = (t >= off) ? tmp[t - off] : 0; __syncthreads();
        tmp[t] += xv; __syncthreads();
    }
    int excl = tmp[t] - s;
#pragma unroll
    for (int q = 0; q < 4; ++q) {
        int idx = base + t * 4 + q;
        if (idx < n) out[idx] = excl;
        excl += v[q];
    }
    if (t == 255) bsum[blockIdx.x] = tmp[255];
}

__global__ __launch_bounds__(256) void scan2_k(int* __restrict__ bsum, int nb) {
    __shared__ int tmp[256];
    int t = threadIdx.x;
    int s = (t < nb) ? bsum[t] : 0;
    tmp[t] = s; __syncthreads();
    for (int off = 1; off < 256; off <<= 1) {
        int xv = (t >= off) ? tmp[t - off] : 0; __syncthreads();
        tmp[t] += xv; __syncthreads();
    }
    if (t < nb) bsum[t] = tmp[t] - s;   // exclusive
}

__global__ __launch_bounds__(256) void scan3_k(int* __restrict__ row_start,
                                               const int* __restrict__ bsum, int n) {
    int i = blockIdx.x * blockDim.x + threadIdx.x;
    if (i < n) row_start[i] += bsum[i >> 10];
}

// binA: partition edges into 1024-wide dst buckets with LDS write-combining.
// Each block = one round of 256*CPT edges. Edges staged per-bucket in LDS,
// flushed in 16-entry (64B) sentinel-padded granules -> full-line HBM writes.
template <int CPT>
__global__ __launch_bounds__(256) void binA_k(const int* __restrict__ src,
                                              const int* __restrict__ dst,
                                              uint* __restrict__ pairs,
                                              int* __restrict__ gcur, int E) {
    __shared__ int  lcur[NBKT];
    __shared__ uint stage[NBKT][CAP_A];
    int t = threadIdx.x;
    int c0 = blockIdx.x * (256 * CPT);
    int n = min(256 * CPT, E - c0);
    for (int i = t; i < NBKT; i += 256) lcur[i] = 0;
    __syncthreads();

    int i0 = t * CPT;
    if (i0 + CPT <= n) {
#pragma unroll
        for (int v = 0; v < CPT / 4; ++v) {
            int4 d4 = *(const int4*)(dst + c0 + i0 + v * 4);
            int4 s4 = *(const int4*)(src + c0 + i0 + v * 4);
            int dv[4] = { d4.x, d4.y, d4.z, d4.w };
            int sv[4] = { s4.x, s4.y, s4.z, s4.w };
#pragma unroll
            for (int q = 0; q < 4; ++q) {
                int d = dv[q];
                int b = d >> 10;
                uint e = ((uint)sv[q] << 10) | (uint)(d & 1023);
                int r = atomicAdd(&lcur[b], 1);
                if (r < CAP_A) stage[b][r] = e;
                else {   // staging overflow (rare): direct global slot
                    int p = atomicAdd(&gcur[b * GSTRIDE], 1);
                    pairs[(size_t)b * BCAP + p] = e;
                }
            }
        }
    } else {
        for (int q = 0; q < CPT; ++q) {
            int i = i0 + q;
            if (i >= n) break;
            int d = dst[c0 + i];
            int b = d >> 10;
            uint e = ((uint)src[c0 + i] << 10) | (uint)(d & 1023);
            int r = atomicAdd(&lcur[b], 1);
            if (r < CAP_A) stage[b][r] = e;
            else {
                int p = atomicAdd(&gcur[b * GSTRIDE], 1);
                pairs[(size_t)b * BCAP + p] = e;
            }
        }
    }
    __syncthreads();

    // flush: one wave per bucket, 16-entry-padded reservation -> 64B-aligned lines
    int wid = t >> 6, lane = t & 63;
    for (int b = wid; b < NBKT; b += 4) {
        int cnt = min(lcur[b], CAP_A);
        if (cnt == 0) continue;
        int padded = (cnt + 15) & ~15;            // 16/32/48 <= 64 lanes
        int base;
        if (lane == 0) base = atomicAdd(&gcur[b * GSTRIDE], padded);
        base = __shfl(base, 0);
        if (lane < padded)
            pairs[(size_t)b * BCAP + base + lane] = (lane < cnt) ? stage[b][lane] : SENT;
    }
}

// binC: per-bucket dst histogram from bucketed pairs (block-local LDS atomics).
// Replaces 3.2M device-scope cnt atomics; writes cnt coalesced (covers all d<nd).
__global__ __launch_bounds__(1024) void binC_k(const uint* __restrict__ pairs,
                                               const int* __restrict__ gcur,
                                               int* __restrict__ cnt, int nd) {
    __shared__ int h[1024];
    int b = blockIdx.x, t = threadIdx.x;
    h[t] = 0;
    __syncthreads();
    int ne = gcur[b * GSTRIDE];
    const uint* bp = pairs + (size_t)b * BCAP;
    for (int i = t; i < ne; i += 1024) {
        uint e = __builtin_nontemporal_load(bp + i);
        if (e != SENT) atomicAdd(&h[e & 1023], 1);
    }
    __syncthreads();
    int d = (b << 10) + t;
    if (d < nd) cnt[d] = h[t];
}

// binB: one block per bucket, LDS per-dst cursors, L2-local csr writes + pad fill
__global__ __launch_bounds__(1024) void binB_k(const uint* __restrict__ pairs,
                                               const int* __restrict__ gcur,
                                               const int* __restrict__ row_start,
                                               int* __restrict__ csr, int nd, int zrow) {
    __shared__ int cur[1024];
    int b = blockIdx.x, t = threadIdx.x;
    int dbase = b << 10;
    cur[t] = (dbase + t < nd) ? row_start[dbase + t] : 0;
    __syncthreads();
    int ne = gcur[b * GSTRIDE];
    const uint* bp = pairs + (size_t)b * BCAP;
    for (int i = t; i < ne; i += 1024) {
        uint e = __builtin_nontemporal_load(bp + i);
        if (e == SENT) continue;
        int p = atomicAdd(&cur[e & 1023], 1);
        csr[p] = (int)(e >> 10);
    }
    __syncthreads();
    // pad each row to a multiple of 4 with the zero-row index (fused fill)
    if (dbase + t < nd) {
        int pe = cur[t];                       // row_start + cnt
        int pad = (-(pe - row_start[dbase + t])) & 3;
        for (int q = 0; q < pad; ++q) csr[pe + q] = zrow;
    }
}

// ---------- gather4: wave per dst row; 16 lanes per src row (uint4/lane),
// 4 rows per wave-load; csr prefetch breaks the csr->h dependency chain. ----
__global__ __launch_bounds__(256) void gather4_k(const int* __restrict__ csr,
                                                 const int* __restrict__ row_start,
                                                 const int* __restrict__ cnt,
                                                 const ushort* __restrict__ hsrc,
                                                 uint* __restrict__ aggm, int nrows) {
    int w    = (blockIdx.x * blockDim.x + threadIdx.x) >> 6;
    int lane = threadIdx.x & 63;
    if (w >= nrows) return;
    int e  = lane >> 4;        // which of 4 edges this lane serves
    int fo = (lane & 15) * 4;  // dword offset within the 64-dword row
    int beg = row_start[w], c = cnt[w];
    int end = beg + ((c + 3) & ~3);
    const uint* hb = (const uint*)hsrc;
    float a[8] = {0.f, 0.f, 0.f, 0.f, 0.f, 0.f, 0.f, 0.f};
    if (beg < end) {
        int r = __builtin_nontemporal_load(csr + beg + e);
        for (int j = beg; j < end; j += 4) {
            int rn = 0;
            if (j + 4 < end) rn = __builtin_nontemporal_load(csr + j + 4 + e);
            uint4 hv = *(const uint4*)(hb + (size_t)r * 64 + fo);
            a[0] += bflo(hv.x); a[1] += bfhi(hv.x);
            a[2] += bflo(hv.y); a[3] += bfhi(hv.y);
            a[4] += bflo(hv.z); a[5] += bfhi(hv.z);
            a[6] += bflo(hv.w); a[7] += bfhi(hv.w);
            r = rn;
        }
    }
    // cross-group reduce: 4 lane-groups hold partial sums of the same features
#pragma unroll
    for (int i = 0; i < 8; ++i) {
        a[i] += __shfl_xor(a[i], 16);
        a[i] += __shfl_xor(a[i], 32);
    }
    if (lane < 16) {
        float inv = 1.0f / fmaxf((float)c, 1.0f);
        uint4 o;
        o.x = pack2(a[0] * inv, a[1] * inv);
        o.y = pack2(a[2] * inv, a[3] * inv);
        o.z = pack2(a[4] * inv, a[5] * inv);
        o.w = pack2(a[6] * inv, a[7] * inv);
        *(uint4*)(aggm + (size_t)w * 64 + fo) = o;
    }
}

// ---------- W pack: [Ws1;Wn1] (256x256 f32) -> B-fragment-major bf16 ----------
__global__ __launch_bounds__(256) void wconv_k(const float* __restrict__ Ws,
                                               const float* __restrict__ Wn,
                                               uint* __restrict__ Wb) {
    int tid  = blockIdx.x * 256 + threadIdx.x;   // 8192 threads
    int lane = tid & 63, nf = (tid >> 6) & 15, ks = tid >> 10;
    int n  = nf * 16 + (lane & 15);
    int k0 = ks * 32 + ((lane >> 4) << 3);
    uint o[4];
#pragma unroll
    for (int p = 0; p < 4; ++p) {
        int k = k0 + 2 * p;
        float a = (k < 128)     ? Ws[(size_t)k * HF + n]       : Wn[(size_t)(k - 128) * HF + n];
        float b = (k + 1 < 128) ? Ws[(size_t)(k + 1) * HF + n] : Wn[(size_t)(k - 127) * HF + n];
        o[p] = pack2(a, b);
    }
    uint4 v = { o[0], o[1], o[2], o[3] };
    *(uint4*)(Wb + (size_t)tid * 4) = v;
}

// ---------- W pack 2: B2 = [Wn2 (cols 0-7) | Ws2 (cols 8-15)], 256x16 bf16 -----
__global__ __launch_bounds__(256) void wpack2_k(const float* __restrict__ Ws2,
                                                const float* __restrict__ Wn2,
                                                uint* __restrict__ Wb2) {
    int tid = blockIdx.x * 256 + threadIdx.x;   // 512 threads
    if (tid >= 512) return;
    int lane = tid & 63, ks = tid >> 6;
    int n  = lane & 15;
    int k0 = ks * 32 + ((lane >> 4) << 3);
    const float* W = (n < 8) ? Wn2 : Ws2;
    int c = n & 7;
    uint o[4];
#pragma unroll
    for (int p = 0; p < 4; ++p) {
        int k = k0 + 2 * p;
        o[p] = pack2(W[(size_t)k * 8 + c], W[(size_t)(k + 1) * 8 + c]);
    }
    uint4 v = { o[0], o[1], o[2], o[3] };
    *(uint4*)(Wb2 + (size_t)tid * 4) = v;
}

// ---------- layer1+zs fused: h1_tile = relu([h|aggm]@Wb + b1) in LDS, then ------
// z = h1@Wn2 and out_self = h1@Ws2 via 8 more MFMAs. h1 never touches global.
__global__ __launch_bounds__(256) void layer1_mfma_k(const uint* __restrict__ hb,
                                                     const uint* __restrict__ aggm,
                                                     const uint* __restrict__ Wb,
                                                     const uint* __restrict__ Wb2,
                                                     const float* __restrict__ b1,
                                                     float* __restrict__ z,
                                                     float* __restrict__ out, int nd1) {
    __shared__ uint lds[64 * 132];   // 33792 B
    int t = threadIdx.x, lane = t & 63, wid = t >> 6;
    int quad = lane >> 4, l16 = lane & 15;
    int r0 = blockIdx.x * 64;

#pragma unroll
    for (int it = 0; it < 8; ++it) {
        int i = t + it * 256;
        int r = i >> 5, u4 = i & 31;
        const uint* src = (u4 < 16) ? (hb + (size_t)(r0 + r) * 64 + u4 * 4)
                                    : (aggm + (size_t)(r0 + r) * 64 + (u4 - 16) * 4);
        *(uint4*)&lds[r * 132 + u4 * 4] = *(const uint4*)src;
    }

    float bias[4];
#pragma unroll
    for (int i = 0; i < 4; ++i) bias[i] = b1[wid * 64 + i * 16 + l16];
    f32x4 acc[4][4];
#pragma unroll
    for (int mf = 0; mf < 4; ++mf)
#pragma unroll
        for (int i = 0; i < 4; ++i)
            acc[mf][i] = (f32x4){ bias[i], bias[i], bias[i], bias[i] };

    __syncthreads();

#pragma unroll
    for (int ks = 0; ks < 8; ++ks) {
        short8 bfr[4];
#pragma unroll
        for (int i = 0; i < 4; ++i) {
            int nf = wid * 4 + i;
            bfr[i] = *(const short8*)(Wb + (size_t)((ks * 16 + nf) * 64 + lane) * 4);
        }
        short8 afr[4];
#pragma unroll
        for (int mf = 0; mf < 4; ++mf) {
            int r = mf * 16 + l16;
            afr[mf] = *(const short8*)&lds[r * 132 + ks * 16 + quad * 4];
        }
#pragma unroll
        for (int mf = 0; mf < 4; ++mf)
#pragma unroll
            for (int i = 0; i < 4; ++i)
                acc[mf][i] = __builtin_amdgcn_mfma_f32_16x16x32_bf16(afr[mf], bfr[i],
                                                                     acc[mf][i], 0, 0, 0);
    }

    __syncthreads();
    // epilogue: relu -> bf16 h1 tile in LDS (ushort stride 264 == dword 132)
    ushort* st = (ushort*)lds;
#pragma unroll
    for (int mf = 0; mf < 4; ++mf)
#pragma unroll
        for (int i = 0; i < 4; ++i) {
            int col = wid * 64 + i * 16 + l16;
#pragma unroll
            for (int reg = 0; reg < 4; ++reg) {
                int row = mf * 16 + quad * 4 + reg;
                st[row * 264 + col] = f2bf(fmaxf(acc[mf][i][reg], 0.0f));
            }
        }
    __syncthreads();

    // fused zs: wave wid handles local rows wid*16..wid*16+15 (K=256 from LDS)
    f32x4 zacc = (f32x4){ 0.f, 0.f, 0.f, 0.f };
    int rloc = wid * 16 + l16;
#pragma unroll
    for (int ks = 0; ks < 8; ++ks) {
        short8 a = *(const short8*)&lds[rloc * 132 + ks * 16 + quad * 4];
        short8 b = *(const short8*)(Wb2 + (size_t)(ks * 64 + lane) * 4);
        zacc = __builtin_amdgcn_mfma_f32_16x16x32_bf16(a, b, zacc, 0, 0, 0);
    }
#pragma unroll
    for (int reg = 0; reg < 4; ++reg) {
        int r = r0 + wid * 16 + quad * 4 + reg;
        if (l16 < 8) z[(size_t)r * 8 + l16] = zacc[reg];
        else if (r < nd1) out[(size_t)r * 8 + (l16 - 8)] = zacc[reg];
    }
}

// ---------- gz: out += mean-gather(z) + b2 ; 8 threads per dst row, prefetch ----
__global__ __launch_bounds__(256) void gz_k(const int* __restrict__ csr,
                                            const int* __restrict__ row_start,
                                            const int* __restrict__ cnt,
                                            const float* __restrict__ z,
                                            const float* __restrict__ b2,
                                            float* __restrict__ out, int nrows) {
    int tid = blockIdx.x * 256 + threadIdx.x;
    int d = tid >> 3, c = tid & 7;
    if (d >= nrows) return;
    int beg = row_start[d], n = cnt[d];
    int end = beg + ((n + 3) & ~3);
    float a = 0.f;
    if (beg < end) {
        int4 s4 = *(const int4*)(csr + beg);
        for (int j = beg; j < end; j += 4) {
            int4 nx = {0, 0, 0, 0};
            if (j + 4 < end) nx = *(const int4*)(csr + j + 4);
            a += z[(size_t)s4.x * 8 + c] + z[(size_t)s4.y * 8 + c]
               + z[(size_t)s4.z * 8 + c] + z[(size_t)s4.w * 8 + c];
            s4 = nx;
        }
    }
    float inv = 1.0f / fmaxf((float)n, 1.0f);
    out[(size_t)d * 8 + c] += a * inv + b2[c];
}

extern "C" void kernel_launch(void* const* d_in, const int* in_sizes, int n_in,
                              void* d_out, int out_size, void* d_ws, size_t ws_size,
                              hipStream_t stream) {
    const float* x    = (const float*)d_in[0];
    const int*   src0 = (const int*)d_in[1];
    const int*   dst0 = (const int*)d_in[2];
    const int*   src1 = (const int*)d_in[3];
    const int*   dst1 = (const int*)d_in[4];
    const float* emb  = (const float*)d_in[7];
    const float* Ws1  = (const float*)d_in[8];
    const float* Wn1  = (const float*)d_in[9];
    const float* b1   = (const float*)d_in[10];
    const float* Ws2  = (const float*)d_in[11];
    const float* Wn2  = (const float*)d_in[12];
    const float* b2   = (const float*)d_in[13];
    int E0 = in_sizes[1];
    int E1 = in_sizes[3];
    int nsrc = in_sizes[0] / 129;   // 400000

    // ---- workspace layout ----
    char* p = (char*)d_ws;
    ushort* h         = (ushort*)p;  p += ((size_t)nsrc + 1) * INF * 2;  // +1 zero row
    uint*   aggm      = (uint*)p;    p += (size_t)ND0 * 64 * 4;          // 51.2 MB
    int*    csr       = (int*)p;     p += ((size_t)E0 + 3 * (size_t)ND0 + 16) * 4;
    int*    cnt       = (int*)p;     p += (size_t)ND0 * 4;
    int*    row_start = (int*)p;     p += (size_t)ND0 * 4;
    int*    bsum      = (int*)p;     p += 256 * 4;
    int*    gcur      = (int*)p;     p += 256 * GSTRIDE * 4;             // 16 KB padded
    uint*   Wb        = (uint*)p;    p += 8192 * 16;
    uint*   Wb2       = (uint*)p;    p += 512 * 16;                      // 8 KB
    float*  z         = (float*)p;   p += ((size_t)ND0 + 1) * 8 * 4;     // +1 zero row
    // pairs overlaid on aggm (dead during CSR build; stream order makes it safe)
    uint*   pairs     = aggm;        // 256*BCAP*4 = 33.5 MB <= 51.2 MB

    int ZR0 = nsrc;   // zero row index in h
    int ZR1 = ND0;    // zero row index in z

    // ---- layer 0/1 ----
    hipMemsetAsync(gcur, 0, 256 * GSTRIDE * 4, stream);
    hipMemsetAsync(h + (size_t)ZR0 * INF, 0, INF * 2, stream);
    gate_k<<<(nsrc * 16 + 255) / 256, 256, 0, stream>>>(x, emb, h, nsrc);
    wconv_k<<<32, 256, 0, stream>>>(Ws1, Wn1, Wb);
    wpack2_k<<<2, 256, 0, stream>>>(Ws2, Wn2, Wb2);
    int nb0 = (ND0 + SCAN_B - 1) / SCAN_B;   // 196
    int ch0 = (E0 + 256 * 16 - 1) / (256 * 16);   // 782 rounds
    binA_k<16><<<ch0, 256, 0, stream>>>(src0, dst0, pairs, gcur, E0);
    binC_k<<<nb0, 1024, 0, stream>>>(pairs, gcur, cnt, ND0);
    scan1_k<<<nb0, 256, 0, stream>>>(cnt, row_start, bsum, ND0);
    scan2_k<<<1, 256, 0, stream>>>(bsum, nb0);
    scan3_k<<<(ND0 + 255) / 256, 256, 0, stream>>>(row_start, bsum, ND0);
    binB_k<<<nb0, 1024, 0, stream>>>(pairs, gcur, row_start, csr, ND0, ZR0);
    gather4_k<<<(ND0 + 3) / 4, 256, 0, stream>>>(csr, row_start, cnt, h, aggm, ND0);
    layer1_mfma_k<<<ND0 / 64, 256, 0, stream>>>((const uint*)h, aggm, Wb, Wb2, b1,
                                                z, (float*)d_out, ND1);

    // ---- layer 2 CSR + neighbor head (z already computed by fused layer1) ----
    hipMemsetAsync(gcur, 0, 256 * GSTRIDE * 4, stream);
    hipMemsetAsync(z + (size_t)ZR1 * 8, 0, 8 * 4, stream);
    int nb1 = (ND1 + SCAN_B - 1) / SCAN_B;   // 98
    int ch1 = (E1 + 256 * 8 - 1) / (256 * 8);    // 782 rounds (chunk 2048)
    binA_k<8><<<ch1, 256, 0, stream>>>(src1, dst1, pairs, gcur, E1);
    binC_k<<<nb1, 1024, 0, stream>>>(pairs, gcur, cnt, ND1);
    scan1_k<<<nb1, 256, 0, stream>>>(cnt, row_start, bsum, ND1);
    scan2_k<<<1, 256, 0, stream>>>(bsum, nb1);
    scan3_k<<<(ND1 + 255) / 256, 256, 0, stream>>>(row_start, bsum, ND1);
    binB_k<<<nb1, 1024, 0, stream>>>(pairs, gcur, row_start, csr, ND1, ZR1);
    gz_k<<<(ND1 * 8 + 255) / 256, 256, 0, stream>>>(csr, row_start, cnt, z, b2,
                                                    (float*)d_out, ND1);
}

// Round 4
// 740.107 us; speedup vs baseline: 1.0300x; 1.0300x over previous
//
#include <hip/hip_runtime.h>

typedef unsigned int uint;
typedef unsigned short ushort;
typedef __attribute__((ext_vector_type(8))) short short8;   // 8 bf16 (4 VGPRs)
typedef __attribute__((ext_vector_type(4))) float f32x4;    // MFMA accumulator

// ---------- bf16 helpers (internal storage only; I/O is fp32) ----------
__device__ __forceinline__ float bflo(uint u) { return __uint_as_float(u << 16); }
__device__ __forceinline__ float bfhi(uint u) { return __uint_as_float(u & 0xffff0000u); }
__device__ __forceinline__ ushort f2bf(float f) {
    uint u = __float_as_uint(f);
    u += 0x7fffu + ((u >> 16) & 1u);   // round-to-nearest-even
    return (ushort)(u >> 16);
}
__device__ __forceinline__ uint pack2(float a, float b) {
    return (uint)f2bf(a) | ((uint)f2bf(b) << 16);
}
__device__ __forceinline__ float sigm(float e) { return 1.0f / (1.0f + __expf(-e)); }

#define ND0 200000
#define ND1 100000
#define INF 128
#define HF  256
#define BCAP 32768   // bucket capacity incl. 16-entry flush padding (worst ~29K)
#define GSTRIDE 16   // gcur padded to 64B/line to avoid same-line atomic serialization
#define NBKT 200     // max 1024-dst buckets (196 for ND0, 98 for ND1)
#define CAP_A 48     // per-bucket LDS staging capacity per round (mean ~21, ~6 sigma)
#define SENT 0xFFFFFFFFu   // pad sentinel; real entries max (400000<<10)|1023 < SENT

// ---------- 1) gate: h[n,f] = feat * sigmoid(emb[cell_id]) ; h bf16 ----------
__global__ __launch_bounds__(256) void gate_k(const float* __restrict__ x,
                                              const float* __restrict__ emb,
                                              ushort* __restrict__ h, int nnodes) {
    int tid  = blockIdx.x * 256 + threadIdx.x;
    int node = tid >> 4, tq = tid & 15;
    if (node >= nnodes) return;
    const float* xr = x + (size_t)node * 129;
    int cell = (int)xr[0];
    int f0 = tq * 8;
    const float* er = emb + cell * INF + f0;
    float4 e0 = *(const float4*)er;
    float4 e1 = *(const float4*)(er + 4);
    float v[8];
    __builtin_memcpy(&v[0], xr + 1 + f0, 16);      // 4B-aligned dwordx4
    __builtin_memcpy(&v[4], xr + 5 + f0, 16);
    uint4 o;
    o.x = pack2(v[0] * sigm(e0.x), v[1] * sigm(e0.y));
    o.y = pack2(v[2] * sigm(e0.z), v[3] * sigm(e0.w));
    o.z = pack2(v[4] * sigm(e1.x), v[5] * sigm(e1.y));
    o.w = pack2(v[6] * sigm(e1.z), v[7] * sigm(e1.w));
    *(uint4*)(h + (size_t)node * INF + f0) = o;
}

// ---------- CSR build ----------
#define SCAN_B 1024
// scans PADDED counts: (cnt+7)&~7 — keeps every CSR row 8-aligned (unroll-2 gather)
__global__ __launch_bounds__(256) void scan1_k(const int* __restrict__ in,
                                               int* __restrict__ out,
                                               int* __restrict__ bsum, int n) {
    __shared__ int tmp[256];
    int t = threadIdx.x;
    int base = blockIdx.x * SCAN_B;
    int v[4], s = 0;
#pragma unroll
    for (int q = 0; q < 4; ++q) {
        int idx = base + t * 4 + q;
        v[q] = (idx < n) ? ((in[idx] + 7) & ~7) : 0;
        s += v[q];
    }
    tmp[t] = s; __syncthreads();
    for (int off = 1; off < 256; off <<= 1) {
        int xv = (t >= off) ? tmp[t - off] : 0; __syncthreads();
        tmp[t] += xv; __syncthreads();
    }
    int excl = tmp[t] - s;
#pragma unroll
    for (int q = 0; q < 4; ++q) {
        int idx = base + t * 4 + q;
        if (idx < n) out[idx] = excl;
        excl += v[q];
    }
    if (t == 255) bsum[blockIdx.x] = tmp[255];
}

__global__ __launch_bounds__(256) void scan2_k(int* __restrict__ bsum, int nb) {
    __shared__ int tmp[256];
    int t = threadIdx.x;
    int s = (t < nb) ? bsum[t] : 0;
    tmp[t] = s; __syncthreads();
    for (int off = 1; off < 256; off <<= 1) {
        int xv = (t >= off) ? tmp[t - off] : 0; __syncthreads();
        tmp[t] += xv; __syncthreads();
    }
    if (t < nb) bsum[t] = tmp[t] - s;   // exclusive
}

__global__ __launch_bounds__(256) void scan3_k(int* __restrict__ row_start,
                                               const int* __restrict__ bsum, int n) {
    int i = blockIdx.x * blockDim.x + threadIdx.x;
    if (i < n) row_start[i] += bsum[i >> 10];
}

// binA: partition edges into 1024-wide dst buckets with LDS write-combining.
// Each block = one round of 256*CPT edges. Edges staged per-bucket in LDS,
// flushed in 16-entry (64B) sentinel-padded granules -> full-line HBM writes.
template <int CPT>
__global__ __launch_bounds__(256) void binA_k(const int* __restrict__ src,
                                              const int* __restrict__ dst,
                                              uint* __restrict__ pairs,
                                              int* __restrict__ gcur, int E) {
    __shared__ int  lcur[NBKT];
    __shared__ uint stage[NBKT][CAP_A];
    int t = threadIdx.x;
    int c0 = blockIdx.x * (256 * CPT);
    int n = min(256 * CPT, E - c0);
    for (int i = t; i < NBKT; i += 256) lcur[i] = 0;
    __syncthreads();

    int i0 = t * CPT;
    if (i0 + CPT <= n) {
#pragma unroll
        for (int v = 0; v < CPT / 4; ++v) {
            int4 d4 = *(const int4*)(dst + c0 + i0 + v * 4);
            int4 s4 = *(const int4*)(src + c0 + i0 + v * 4);
            int dv[4] = { d4.x, d4.y, d4.z, d4.w };
            int sv[4] = { s4.x, s4.y, s4.z, s4.w };
#pragma unroll
            for (int q = 0; q < 4; ++q) {
                int d = dv[q];
                int b = d >> 10;
                uint e = ((uint)sv[q] << 10) | (uint)(d & 1023);
                int r = atomicAdd(&lcur[b], 1);
                if (r < CAP_A) stage[b][r] = e;
                else {   // staging overflow (rare): direct global slot
                    int p = atomicAdd(&gcur[b * GSTRIDE], 1);
                    pairs[(size_t)b * BCAP + p] = e;
                }
            }
        }
    } else {
        for (int q = 0; q < CPT; ++q) {
            int i = i0 + q;
            if (i >= n) break;
            int d = dst[c0 + i];
            int b = d >> 10;
            uint e = ((uint)src[c0 + i] << 10) | (uint)(d & 1023);
            int r = atomicAdd(&lcur[b], 1);
            if (r < CAP_A) stage[b][r] = e;
            else {
                int p = atomicAdd(&gcur[b * GSTRIDE], 1);
                pairs[(size_t)b * BCAP + p] = e;
            }
        }
    }
    __syncthreads();

    // flush: one wave per bucket, 16-entry-padded reservation -> 64B-aligned lines
    int wid = t >> 6, lane = t & 63;
    for (int b = wid; b < NBKT; b += 4) {
        int cnt = min(lcur[b], CAP_A);
        if (cnt == 0) continue;
        int padded = (cnt + 15) & ~15;            // 16/32/48 <= 64 lanes
        int base;
        if (lane == 0) base = atomicAdd(&gcur[b * GSTRIDE], padded);
        base = __shfl(base, 0);
        if (lane < padded)
            pairs[(size_t)b * BCAP + base + lane] = (lane < cnt) ? stage[b][lane] : SENT;
    }
}

// binC: per-bucket dst histogram from bucketed pairs (block-local LDS atomics).
__global__ __launch_bounds__(1024) void binC_k(const uint* __restrict__ pairs,
                                               const int* __restrict__ gcur,
                                               int* __restrict__ cnt, int nd) {
    __shared__ int h[1024];
    int b = blockIdx.x, t = threadIdx.x;
    h[t] = 0;
    __syncthreads();
    int ne = gcur[b * GSTRIDE];
    const uint* bp = pairs + (size_t)b * BCAP;
    for (int i = t; i < ne; i += 1024) {
        uint e = __builtin_nontemporal_load(bp + i);
        if (e != SENT) atomicAdd(&h[e & 1023], 1);
    }
    __syncthreads();
    int d = (b << 10) + t;
    if (d < nd) cnt[d] = h[t];
}

// binB: one block per bucket, LDS per-dst cursors, L2-local csr writes + pad fill
__global__ __launch_bounds__(1024) void binB_k(const uint* __restrict__ pairs,
                                               const int* __restrict__ gcur,
                                               const int* __restrict__ row_start,
                                               int* __restrict__ csr, int nd, int zrow) {
    __shared__ int cur[1024];
    int b = blockIdx.x, t = threadIdx.x;
    int dbase = b << 10;
    cur[t] = (dbase + t < nd) ? row_start[dbase + t] : 0;
    __syncthreads();
    int ne = gcur[b * GSTRIDE];
    const uint* bp = pairs + (size_t)b * BCAP;
    for (int i = t; i < ne; i += 1024) {
        uint e = __builtin_nontemporal_load(bp + i);
        if (e == SENT) continue;
        int p = atomicAdd(&cur[e & 1023], 1);
        csr[p] = (int)(e >> 10);
    }
    __syncthreads();
    // pad each row to a multiple of 8 with the zero-row index (fused fill)
    if (dbase + t < nd) {
        int pe = cur[t];                       // row_start + cnt
        int pad = (-(pe - row_start[dbase + t])) & 7;
        for (int q = 0; q < pad; ++q) csr[pe + q] = zrow;
    }
}

// ---------- gather4: wave per dst row; 16 lanes per src row (uint4/lane);
// unroll-2 over 8-padded rows -> 2 KB in flight per wave (MLP x2). ----------
__global__ __launch_bounds__(256) void gather4_k(const int* __restrict__ csr,
                                                 const int* __restrict__ row_start,
                                                 const int* __restrict__ cnt,
                                                 const ushort* __restrict__ hsrc,
                                                 uint* __restrict__ aggm, int nrows) {
    int w    = (blockIdx.x * blockDim.x + threadIdx.x) >> 6;
    int lane = threadIdx.x & 63;
    if (w >= nrows) return;
    int e  = lane >> 4;        // edge slot 0..3 within each group of 4
    int fo = (lane & 15) * 4;  // dword offset within the 64-dword row
    int beg = row_start[w], c = cnt[w];
    int end = beg + ((c + 7) & ~7);
    const uint* hb = (const uint*)hsrc;
    float a[8] = {0.f, 0.f, 0.f, 0.f, 0.f, 0.f, 0.f, 0.f};
    if (beg < end) {
        int r0 = csr[beg + e];
        int r1 = csr[beg + 4 + e];
        for (int j = beg; j < end; j += 8) {
            int n0 = 0, n1 = 0;
            if (j + 8 < end) {
                n0 = csr[j + 8 + e];
                n1 = csr[j + 12 + e];
            }
            uint4 h0 = *(const uint4*)(hb + (size_t)r0 * 64 + fo);
            uint4 h1 = *(const uint4*)(hb + (size_t)r1 * 64 + fo);
            a[0] += bflo(h0.x) + bflo(h1.x); a[1] += bfhi(h0.x) + bfhi(h1.x);
            a[2] += bflo(h0.y) + bflo(h1.y); a[3] += bfhi(h0.y) + bfhi(h1.y);
            a[4] += bflo(h0.z) + bflo(h1.z); a[5] += bfhi(h0.z) + bfhi(h1.z);
            a[6] += bflo(h0.w) + bflo(h1.w); a[7] += bfhi(h0.w) + bfhi(h1.w);
            r0 = n0; r1 = n1;
        }
    }
    // cross-group reduce: 4 lane-groups hold partial sums of the same features
#pragma unroll
    for (int i = 0; i < 8; ++i) {
        a[i] += __shfl_xor(a[i], 16);
        a[i] += __shfl_xor(a[i], 32);
    }
    if (lane < 16) {
        float inv = 1.0f / fmaxf((float)c, 1.0f);
        uint4 o;
        o.x = pack2(a[0] * inv, a[1] * inv);
        o.y = pack2(a[2] * inv, a[3] * inv);
        o.z = pack2(a[4] * inv, a[5] * inv);
        o.w = pack2(a[6] * inv, a[7] * inv);
        *(uint4*)(aggm + (size_t)w * 64 + fo) = o;
    }
}

// ---------- W pack: [Ws1;Wn1] (256x256 f32) -> B-fragment-major bf16 ----------
__global__ __launch_bounds__(256) void wconv_k(const float* __restrict__ Ws,
                                               const float* __restrict__ Wn,
                                               uint* __restrict__ Wb) {
    int tid  = blockIdx.x * 256 + threadIdx.x;   // 8192 threads
    int lane = tid & 63, nf = (tid >> 6) & 15, ks = tid >> 10;
    int n  = nf * 16 + (lane & 15);
    int k0 = ks * 32 + ((lane >> 4) << 3);
    uint o[4];
#pragma unroll
    for (int p = 0; p < 4; ++p) {
        int k = k0 + 2 * p;
        float a = (k < 128)     ? Ws[(size_t)k * HF + n]       : Wn[(size_t)(k - 128) * HF + n];
        float b = (k + 1 < 128) ? Ws[(size_t)(k + 1) * HF + n] : Wn[(size_t)(k - 127) * HF + n];
        o[p] = pack2(a, b);
    }
    uint4 v = { o[0], o[1], o[2], o[3] };
    *(uint4*)(Wb + (size_t)tid * 4) = v;
}

// ---------- W pack 2: B2 = [Wn2 (cols 0-7) | Ws2 (cols 8-15)], 256x16 bf16 -----
__global__ __launch_bounds__(256) void wpack2_k(const float* __restrict__ Ws2,
                                                const float* __restrict__ Wn2,
                                                uint* __restrict__ Wb2) {
    int tid = blockIdx.x * 256 + threadIdx.x;   // 512 threads
    if (tid >= 512) return;
    int lane = tid & 63, ks = tid >> 6;
    int n  = lane & 15;
    int k0 = ks * 32 + ((lane >> 4) << 3);
    const float* W = (n < 8) ? Wn2 : Ws2;
    int c = n & 7;
    uint o[4];
#pragma unroll
    for (int p = 0; p < 4; ++p) {
        int k = k0 + 2 * p;
        o[p] = pack2(W[(size_t)k * 8 + c], W[(size_t)(k + 1) * 8 + c]);
    }
    uint4 v = { o[0], o[1], o[2], o[3] };
    *(uint4*)(Wb2 + (size_t)tid * 4) = v;
}

// ---------- layer1+zs fused: h1_tile = relu([h|aggm]@Wb + b1) in LDS, then ------
// z = h1@Wn2 and out_self = h1@Ws2 via 8 more MFMAs. h1 never touches global.
__global__ __launch_bounds__(256) void layer1_mfma_k(const uint* __restrict__ hb,
                                                     const uint* __restrict__ aggm,
                                                     const uint* __restrict__ Wb,
                                                     const uint* __restrict__ Wb2,
                                                     const float* __restrict__ b1,
                                                     float* __restrict__ z,
                                                     float* __restrict__ out, int nd1) {
    __shared__ uint lds[64 * 132];   // 33792 B
    int t = threadIdx.x, lane = t & 63, wid = t >> 6;
    int quad = lane >> 4, l16 = lane & 15;
    int r0 = blockIdx.x * 64;

#pragma unroll
    for (int it = 0; it < 8; ++it) {
        int i = t + it * 256;
        int r = i >> 5, u4 = i & 31;
        const uint* src = (u4 < 16) ? (hb + (size_t)(r0 + r) * 64 + u4 * 4)
                                    : (aggm + (size_t)(r0 + r) * 64 + (u4 - 16) * 4);
        *(uint4*)&lds[r * 132 + u4 * 4] = *(const uint4*)src;
    }

    float bias[4];
#pragma unroll
    for (int i = 0; i < 4; ++i) bias[i] = b1[wid * 64 + i * 16 + l16];
    f32x4 acc[4][4];
#pragma unroll
    for (int mf = 0; mf < 4; ++mf)
#pragma unroll
        for (int i = 0; i < 4; ++i)
            acc[mf][i] = (f32x4){ bias[i], bias[i], bias[i], bias[i] };

    __syncthreads();

#pragma unroll
    for (int ks = 0; ks < 8; ++ks) {
        short8 bfr[4];
#pragma unroll
        for (int i = 0; i < 4; ++i) {
            int nf = wid * 4 + i;
            bfr[i] = *(const short8*)(Wb + (size_t)((ks * 16 + nf) * 64 + lane) * 4);
        }
        short8 afr[4];
#pragma unroll
        for (int mf = 0; mf < 4; ++mf) {
            int r = mf * 16 + l16;
            afr[mf] = *(const short8*)&lds[r * 132 + ks * 16 + quad * 4];
        }
#pragma unroll
        for (int mf = 0; mf < 4; ++mf)
#pragma unroll
            for (int i = 0; i < 4; ++i)
                acc[mf][i] = __builtin_amdgcn_mfma_f32_16x16x32_bf16(afr[mf], bfr[i],
                                                                     acc[mf][i], 0, 0, 0);
    }

    __syncthreads();
    // epilogue: relu -> bf16 h1 tile in LDS (ushort stride 264 == dword 132)
    ushort* st = (ushort*)lds;
#pragma unroll
    for (int mf = 0; mf < 4; ++mf)
#pragma unroll
        for (int i = 0; i < 4; ++i) {
            int col = wid * 64 + i * 16 + l16;
#pragma unroll
            for (int reg = 0; reg < 4; ++reg) {
                int row = mf * 16 + quad * 4 + reg;
                st[row * 264 + col] = f2bf(fmaxf(acc[mf][i][reg], 0.0f));
            }
        }
    __syncthreads();

    // fused zs: wave wid handles local rows wid*16..wid*16+15 (K=256 from LDS)
    f32x4 zacc = (f32x4){ 0.f, 0.f, 0.f, 0.f };
    int rloc = wid * 16 + l16;
#pragma unroll
    for (int ks = 0; ks < 8; ++ks) {
        short8 a = *(const short8*)&lds[rloc * 132 + ks * 16 + quad * 4];
        short8 b = *(const short8*)(Wb2 + (size_t)(ks * 64 + lane) * 4);
        zacc = __builtin_amdgcn_mfma_f32_16x16x32_bf16(a, b, zacc, 0, 0, 0);
    }
#pragma unroll
    for (int reg = 0; reg < 4; ++reg) {
        int r = r0 + wid * 16 + quad * 4 + reg;
        if (l16 < 8) z[(size_t)r * 8 + l16] = zacc[reg];
        else if (r < nd1) out[(size_t)r * 8 + (l16 - 8)] = zacc[reg];
    }
}

// ---------- gz: out += mean-gather(z) + b2 ; 8 threads per dst row ----
__global__ __launch_bounds__(256) void gz_k(const int* __restrict__ csr,
                                            const int* __restrict__ row_start,
                                            const int* __restrict__ cnt,
                                            const float* __restrict__ z,
                                            const float* __restrict__ b2,
                                            float* __restrict__ out, int nrows) {
    int tid = blockIdx.x * 256 + threadIdx.x;
    int d = tid >> 3, c = tid & 7;
    if (d >= nrows) return;
    int beg = row_start[d], n = cnt[d];
    int end = beg + ((n + 3) & ~3);   // 8-padded rows: pads beyond this hit zero row anyway
    float a = 0.f;
    for (int j = beg; j < end; j += 4) {
        int4 s4 = *(const int4*)(csr + j);     // pad slots -> zero z row
        a += z[(size_t)s4.x * 8 + c] + z[(size_t)s4.y * 8 + c]
           + z[(size_t)s4.z * 8 + c] + z[(size_t)s4.w * 8 + c];
    }
    float inv = 1.0f / fmaxf((float)n, 1.0f);
    out[(size_t)d * 8 + c] += a * inv + b2[c];
}

extern "C" void kernel_launch(void* const* d_in, const int* in_sizes, int n_in,
                              void* d_out, int out_size, void* d_ws, size_t ws_size,
                              hipStream_t stream) {
    const float* x    = (const float*)d_in[0];
    const int*   src0 = (const int*)d_in[1];
    const int*   dst0 = (const int*)d_in[2];
    const int*   src1 = (const int*)d_in[3];
    const int*   dst1 = (const int*)d_in[4];
    const float* emb  = (const float*)d_in[7];
    const float* Ws1  = (const float*)d_in[8];
    const float* Wn1  = (const float*)d_in[9];
    const float* b1   = (const float*)d_in[10];
    const float* Ws2  = (const float*)d_in[11];
    const float* Wn2  = (const float*)d_in[12];
    const float* b2   = (const float*)d_in[13];
    int E0 = in_sizes[1];
    int E1 = in_sizes[3];
    int nsrc = in_sizes[0] / 129;   // 400000

    // ---- workspace layout ----
    char* p = (char*)d_ws;
    ushort* h         = (ushort*)p;  p += ((size_t)nsrc + 1) * INF * 2;  // +1 zero row
    uint*   aggm      = (uint*)p;    p += (size_t)ND0 * 64 * 4;          // 51.2 MB
    int*    csr       = (int*)p;     p += ((size_t)E0 + 7 * (size_t)ND0 + 16) * 4;
    int*    cnt       = (int*)p;     p += (size_t)ND0 * 4;
    int*    row_start = (int*)p;     p += (size_t)ND0 * 4;
    int*    bsum      = (int*)p;     p += 256 * 4;
    int*    gcur      = (int*)p;     p += 256 * GSTRIDE * 4;             // 16 KB padded
    uint*   Wb        = (uint*)p;    p += 8192 * 16;
    uint*   Wb2       = (uint*)p;    p += 512 * 16;                      // 8 KB
    float*  z         = (float*)p;   p += ((size_t)ND0 + 1) * 8 * 4;     // +1 zero row
    // pairs overlaid on aggm (dead during CSR build; stream order makes it safe)
    uint*   pairs     = aggm;        // 256*BCAP*4 = 33.5 MB <= 51.2 MB

    int ZR0 = nsrc;   // zero row index in h
    int ZR1 = ND0;    // zero row index in z

    // ---- layer 0/1 ----
    hipMemsetAsync(gcur, 0, 256 * GSTRIDE * 4, stream);
    hipMemsetAsync(h + (size_t)ZR0 * INF, 0, INF * 2, stream);
    gate_k<<<(nsrc * 16 + 255) / 256, 256, 0, stream>>>(x, emb, h, nsrc);
    wconv_k<<<32, 256, 0, stream>>>(Ws1, Wn1, Wb);
    wpack2_k<<<2, 256, 0, stream>>>(Ws2, Wn2, Wb2);
    int nb0 = (ND0 + SCAN_B - 1) / SCAN_B;   // 196
    int ch0 = (E0 + 256 * 16 - 1) / (256 * 16);   // 782 rounds
    binA_k<16><<<ch0, 256, 0, stream>>>(src0, dst0, pairs, gcur, E0);
    binC_k<<<nb0, 1024, 0, stream>>>(pairs, gcur, cnt, ND0);
    scan1_k<<<nb0, 256, 0, stream>>>(cnt, row_start, bsum, ND0);
    scan2_k<<<1, 256, 0, stream>>>(bsum, nb0);
    scan3_k<<<(ND0 + 255) / 256, 256, 0, stream>>>(row_start, bsum, ND0);
    binB_k<<<nb0, 1024, 0, stream>>>(pairs, gcur, row_start, csr, ND0, ZR0);
    gather4_k<<<(ND0 + 3) / 4, 256, 0, stream>>>(csr, row_start, cnt, h, aggm, ND0);
    layer1_mfma_k<<<ND0 / 64, 256, 0, stream>>>((const uint*)h, aggm, Wb, Wb2, b1,
                                                z, (float*)d_out, ND1);

    // ---- layer 2 CSR + neighbor head (z already computed by fused layer1) ----
    hipMemsetAsync(gcur, 0, 256 * GSTRIDE * 4, stream);
    hipMemsetAsync(z + (size_t)ZR1 * 8, 0, 8 * 4, stream);
    int nb1 = (ND1 + SCAN_B - 1) / SCAN_B;   // 98
    int ch1 = (E1 + 256 * 8 - 1) / (256 * 8);    // 782 rounds (chunk 2048)
    binA_k<8><<<ch1, 256, 0, stream>>>(src1, dst1, pairs, gcur, E1);
    binC_k<<<nb1, 1024, 0, stream>>>(pairs, gcur, cnt, ND1);
    scan1_k<<<nb1, 256, 0, stream>>>(cnt, row_start, bsum, ND1);
    scan2_k<<<1, 256, 0, stream>>>(bsum, nb1);
    scan3_k<<<(ND1 + 255) / 256, 256, 0, stream>>>(row_start, bsum, ND1);
    binB_k<<<nb1, 1024, 0, stream>>>(pairs, gcur, row_start, csr, ND1, ZR1);
    gz_k<<<(ND1 * 8 + 255) / 256, 256, 0, stream>>>(csr, row_start, cnt, z, b2,
                                                    (float*)d_out, ND1);
}

// Round 5
// 724.110 us; speedup vs baseline: 1.0528x; 1.0221x over previous
//
#include <hip/hip_runtime.h>

typedef unsigned int uint;
typedef unsigned short ushort;
typedef __attribute__((ext_vector_type(8))) short short8;   // 8 bf16 (4 VGPRs)
typedef __attribute__((ext_vector_type(4))) float f32x4;    // MFMA accumulator
typedef __attribute__((ext_vector_type(2))) float f32x2;    // v_pk_add_f32 pair

// ---------- bf16 helpers (internal storage only; I/O is fp32) ----------
__device__ __forceinline__ float bflo(uint u) { return __uint_as_float(u << 16); }
__device__ __forceinline__ float bfhi(uint u) { return __uint_as_float(u & 0xffff0000u); }
__device__ __forceinline__ ushort f2bf(float f) {
    uint u = __float_as_uint(f);
    u += 0x7fffu + ((u >> 16) & 1u);   // round-to-nearest-even
    return (ushort)(u >> 16);
}
__device__ __forceinline__ uint pack2(float a, float b) {
    return (uint)f2bf(a) | ((uint)f2bf(b) << 16);
}
__device__ __forceinline__ float sigm(float e) { return 1.0f / (1.0f + __expf(-e)); }

#define ND0 200000
#define ND1 100000
#define INF 128
#define HF  256
#define BCAP 32768   // bucket capacity incl. 16-entry flush padding (worst ~29K)
#define GSTRIDE 16   // gcur padded to 64B/line to avoid same-line atomic serialization
#define NBKT 200     // max 1024-dst buckets (196 for ND0, 98 for ND1)
#define CAP_A 48     // per-bucket LDS staging capacity per round (mean ~21, ~6 sigma)
#define SENT 0xFFFFFFFFu   // pad sentinel; real entries max (400000<<10)|1023 < SENT

// ---------- 1) gate: h[n,f] = feat * sigmoid(emb[cell_id]) ; h bf16 ----------
__global__ __launch_bounds__(256) void gate_k(const float* __restrict__ x,
                                              const float* __restrict__ emb,
                                              ushort* __restrict__ h, int nnodes) {
    int tid  = blockIdx.x * 256 + threadIdx.x;
    int node = tid >> 4, tq = tid & 15;
    if (node >= nnodes) return;
    const float* xr = x + (size_t)node * 129;
    int cell = (int)xr[0];
    int f0 = tq * 8;
    const float* er = emb + cell * INF + f0;
    float4 e0 = *(const float4*)er;
    float4 e1 = *(const float4*)(er + 4);
    float v[8];
    __builtin_memcpy(&v[0], xr + 1 + f0, 16);      // 4B-aligned dwordx4
    __builtin_memcpy(&v[4], xr + 5 + f0, 16);
    uint4 o;
    o.x = pack2(v[0] * sigm(e0.x), v[1] * sigm(e0.y));
    o.y = pack2(v[2] * sigm(e0.z), v[3] * sigm(e0.w));
    o.z = pack2(v[4] * sigm(e1.x), v[5] * sigm(e1.y));
    o.w = pack2(v[6] * sigm(e1.z), v[7] * sigm(e1.w));
    *(uint4*)(h + (size_t)node * INF + f0) = o;
}

// ---------- CSR build ----------
#define SCAN_B 1024
// scans PADDED counts: (cnt+7)&~7 — keeps every CSR row 8-aligned (unroll-2 gather)
__global__ __launch_bounds__(256) void scan1_k(const int* __restrict__ in,
                                               int* __restrict__ out,
                                               int* __restrict__ bsum, int n) {
    __shared__ int tmp[256];
    int t = threadIdx.x;
    int base = blockIdx.x * SCAN_B;
    int v[4], s = 0;
#pragma unroll
    for (int q = 0; q < 4; ++q) {
        int idx = base + t * 4 + q;
        v[q] = (idx < n) ? ((in[idx] + 7) & ~7) : 0;
        s += v[q];
    }
    tmp[t] = s; __syncthreads();
    for (int off = 1; off < 256; off <<= 1) {
        int xv = (t >= off) ? tmp[t - off] : 0; __syncthreads();
        tmp[t] += xv; __syncthreads();
    }
    int excl = tmp[t] - s;
#pragma unroll
    for (int q = 0; q < 4; ++q) {
        int idx = base + t * 4 + q;
        if (idx < n) out[idx] = excl;
        excl += v[q];
    }
    if (t == 255) bsum[blockIdx.x] = tmp[255];
}

__global__ __launch_bounds__(256) void scan2_k(int* __restrict__ bsum, int nb) {
    __shared__ int tmp[256];
    int t = threadIdx.x;
    int s = (t < nb) ? bsum[t] : 0;
    tmp[t] = s; __syncthreads();
    for (int off = 1; off < 256; off <<= 1) {
        int xv = (t >= off) ? tmp[t - off] : 0; __syncthreads();
        tmp[t] += xv; __syncthreads();
    }
    if (t < nb) bsum[t] = tmp[t] - s;   // exclusive
}

__global__ __launch_bounds__(256) void scan3_k(int* __restrict__ row_start,
                                               const int* __restrict__ bsum, int n) {
    int i = blockIdx.x * blockDim.x + threadIdx.x;
    if (i < n) row_start[i] += bsum[i >> 10];
}

// binA: partition edges into 1024-wide dst buckets with LDS write-combining.
// Each block = one round of 256*CPT edges. Edges staged per-bucket in LDS,
// flushed in 16-entry (64B) sentinel-padded granules -> full-line HBM writes.
template <int CPT>
__global__ __launch_bounds__(256) void binA_k(const int* __restrict__ src,
                                              const int* __restrict__ dst,
                                              uint* __restrict__ pairs,
                                              int* __restrict__ gcur, int E) {
    __shared__ int  lcur[NBKT];
    __shared__ uint stage[NBKT][CAP_A];
    int t = threadIdx.x;
    int c0 = blockIdx.x * (256 * CPT);
    int n = min(256 * CPT, E - c0);
    for (int i = t; i < NBKT; i += 256) lcur[i] = 0;
    __syncthreads();

    int i0 = t * CPT;
    if (i0 + CPT <= n) {
#pragma unroll
        for (int v = 0; v < CPT / 4; ++v) {
            int4 d4 = *(const int4*)(dst + c0 + i0 + v * 4);
            int4 s4 = *(const int4*)(src + c0 + i0 + v * 4);
            int dv[4] = { d4.x, d4.y, d4.z, d4.w };
            int sv[4] = { s4.x, s4.y, s4.z, s4.w };
#pragma unroll
            for (int q = 0; q < 4; ++q) {
                int d = dv[q];
                int b = d >> 10;
                uint e = ((uint)sv[q] << 10) | (uint)(d & 1023);
                int r = atomicAdd(&lcur[b], 1);
                if (r < CAP_A) stage[b][r] = e;
                else {   // staging overflow (rare): direct global slot
                    int p = atomicAdd(&gcur[b * GSTRIDE], 1);
                    pairs[(size_t)b * BCAP + p] = e;
                }
            }
        }
    } else {
        for (int q = 0; q < CPT; ++q) {
            int i = i0 + q;
            if (i >= n) break;
            int d = dst[c0 + i];
            int b = d >> 10;
            uint e = ((uint)src[c0 + i] << 10) | (uint)(d & 1023);
            int r = atomicAdd(&lcur[b], 1);
            if (r < CAP_A) stage[b][r] = e;
            else {
                int p = atomicAdd(&gcur[b * GSTRIDE], 1);
                pairs[(size_t)b * BCAP + p] = e;
            }
        }
    }
    __syncthreads();

    // flush: one wave per bucket, 16-entry-padded reservation -> 64B-aligned lines
    int wid = t >> 6, lane = t & 63;
    for (int b = wid; b < NBKT; b += 4) {
        int cnt = min(lcur[b], CAP_A);
        if (cnt == 0) continue;
        int padded = (cnt + 15) & ~15;            // 16/32/48 <= 64 lanes
        int base;
        if (lane == 0) base = atomicAdd(&gcur[b * GSTRIDE], padded);
        base = __shfl(base, 0);
        if (lane < padded)
            pairs[(size_t)b * BCAP + base + lane] = (lane < cnt) ? stage[b][lane] : SENT;
    }
}

// binC: per-bucket dst histogram from bucketed pairs (block-local LDS atomics).
__global__ __launch_bounds__(1024) void binC_k(const uint* __restrict__ pairs,
                                               const int* __restrict__ gcur,
                                               int* __restrict__ cnt, int nd) {
    __shared__ int h[1024];
    int b = blockIdx.x, t = threadIdx.x;
    h[t] = 0;
    __syncthreads();
    int ne = gcur[b * GSTRIDE];
    const uint* bp = pairs + (size_t)b * BCAP;
    for (int i = t; i < ne; i += 1024) {
        uint e = bp[i];
        if (e != SENT) atomicAdd(&h[e & 1023], 1);
    }
    __syncthreads();
    int d = (b << 10) + t;
    if (d < nd) cnt[d] = h[t];
}

// binB: one block per bucket, LDS per-dst cursors, L2-local csr writes + pad fill
__global__ __launch_bounds__(1024) void binB_k(const uint* __restrict__ pairs,
                                               const int* __restrict__ gcur,
                                               const int* __restrict__ row_start,
                                               int* __restrict__ csr, int nd, int zrow) {
    __shared__ int cur[1024];
    int b = blockIdx.x, t = threadIdx.x;
    int dbase = b << 10;
    cur[t] = (dbase + t < nd) ? row_start[dbase + t] : 0;
    __syncthreads();
    int ne = gcur[b * GSTRIDE];
    const uint* bp = pairs + (size_t)b * BCAP;
    for (int i = t; i < ne; i += 1024) {
        uint e = bp[i];
        if (e == SENT) continue;
        int p = atomicAdd(&cur[e & 1023], 1);
        csr[p] = (int)(e >> 10);
    }
    __syncthreads();
    // pad each row to a multiple of 8 with the zero-row index (fused fill)
    if (dbase + t < nd) {
        int pe = cur[t];                       // row_start + cnt
        int pad = (-(pe - row_start[dbase + t])) & 7;
        for (int q = 0; q < pad; ++q) csr[pe + q] = zrow;
    }
}

// ---------- gather4: wave per dst row; 16 lanes per src row (uint4/lane);
// depth-2 software pipeline (next iter's 2 row-loads issued before consuming
// current) -> ~4KB in flight/wave; f32x2 accumulators -> v_pk_add_f32. ----------
__global__ __launch_bounds__(256) void gather4_k(const int* __restrict__ csr,
                                                 const int* __restrict__ row_start,
                                                 const int* __restrict__ cnt,
                                                 const ushort* __restrict__ hsrc,
                                                 uint* __restrict__ aggm, int nrows) {
    int w    = (blockIdx.x * blockDim.x + threadIdx.x) >> 6;
    int lane = threadIdx.x & 63;
    if (w >= nrows) return;
    int e  = lane >> 4;        // edge slot 0..3 within each group of 4
    int fo = (lane & 15) * 4;  // dword offset within the 64-dword row
    int beg = row_start[w], c = cnt[w];
    int end = beg + ((c + 7) & ~7);
    const uint* hb = (const uint*)hsrc;
    f32x2 A[4] = {{0.f,0.f},{0.f,0.f},{0.f,0.f},{0.f,0.f}};
    f32x2 B[4] = {{0.f,0.f},{0.f,0.f},{0.f,0.f},{0.f,0.f}};
    if (beg < end) {
        int r0 = csr[beg + e];
        int r1 = csr[beg + 4 + e];
        uint4 h0 = *(const uint4*)(hb + (size_t)r0 * 64 + fo);
        uint4 h1 = *(const uint4*)(hb + (size_t)r1 * 64 + fo);
        for (int j = beg; j < end; j += 8) {
            int n0 = 0, n1 = 0;
            if (j + 8 < end) {
                n0 = csr[j + 8 + e];
                n1 = csr[j + 12 + e];
            }
            // issue next iteration's loads BEFORE consuming current (vmcnt(2) wait)
            uint4 g0 = *(const uint4*)(hb + (size_t)n0 * 64 + fo);
            uint4 g1 = *(const uint4*)(hb + (size_t)n1 * 64 + fo);
            A[0] += (f32x2){ bflo(h0.x), bfhi(h0.x) };
            A[1] += (f32x2){ bflo(h0.y), bfhi(h0.y) };
            A[2] += (f32x2){ bflo(h0.z), bfhi(h0.z) };
            A[3] += (f32x2){ bflo(h0.w), bfhi(h0.w) };
            B[0] += (f32x2){ bflo(h1.x), bfhi(h1.x) };
            B[1] += (f32x2){ bflo(h1.y), bfhi(h1.y) };
            B[2] += (f32x2){ bflo(h1.z), bfhi(h1.z) };
            B[3] += (f32x2){ bflo(h1.w), bfhi(h1.w) };
            h0 = g0; h1 = g1;
        }
    }
#pragma unroll
    for (int i = 0; i < 4; ++i) A[i] += B[i];
    // cross-group reduce: 4 lane-groups hold partial sums of the same features
#pragma unroll
    for (int i = 0; i < 4; ++i) {
        A[i].x += __shfl_xor(A[i].x, 16);
        A[i].y += __shfl_xor(A[i].y, 16);
        A[i].x += __shfl_xor(A[i].x, 32);
        A[i].y += __shfl_xor(A[i].y, 32);
    }
    if (lane < 16) {
        float inv = 1.0f / fmaxf((float)c, 1.0f);
        uint4 o;
        o.x = pack2(A[0].x * inv, A[0].y * inv);
        o.y = pack2(A[1].x * inv, A[1].y * inv);
        o.z = pack2(A[2].x * inv, A[2].y * inv);
        o.w = pack2(A[3].x * inv, A[3].y * inv);
        *(uint4*)(aggm + (size_t)w * 64 + fo) = o;
    }
}

// ---------- W pack: [Ws1;Wn1] (256x256 f32) -> B-fragment-major bf16 ----------
__global__ __launch_bounds__(256) void wconv_k(const float* __restrict__ Ws,
                                               const float* __restrict__ Wn,
                                               uint* __restrict__ Wb) {
    int tid  = blockIdx.x * 256 + threadIdx.x;   // 8192 threads
    int lane = tid & 63, nf = (tid >> 6) & 15, ks = tid >> 10;
    int n  = nf * 16 + (lane & 15);
    int k0 = ks * 32 + ((lane >> 4) << 3);
    uint o[4];
#pragma unroll
    for (int p = 0; p < 4; ++p) {
        int k = k0 + 2 * p;
        float a = (k < 128)     ? Ws[(size_t)k * HF + n]       : Wn[(size_t)(k - 128) * HF + n];
        float b = (k + 1 < 128) ? Ws[(size_t)(k + 1) * HF + n] : Wn[(size_t)(k - 127) * HF + n];
        o[p] = pack2(a, b);
    }
    uint4 v = { o[0], o[1], o[2], o[3] };
    *(uint4*)(Wb + (size_t)tid * 4) = v;
}

// ---------- W pack 2: B2 = [Wn2 (cols 0-7) | Ws2 (cols 8-15)], 256x16 bf16 -----
__global__ __launch_bounds__(256) void wpack2_k(const float* __restrict__ Ws2,
                                                const float* __restrict__ Wn2,
                                                uint* __restrict__ Wb2) {
    int tid = blockIdx.x * 256 + threadIdx.x;   // 512 threads
    if (tid >= 512) return;
    int lane = tid & 63, ks = tid >> 6;
    int n  = lane & 15;
    int k0 = ks * 32 + ((lane >> 4) << 3);
    const float* W = (n < 8) ? Wn2 : Ws2;
    int c = n & 7;
    uint o[4];
#pragma unroll
    for (int p = 0; p < 4; ++p) {
        int k = k0 + 2 * p;
        o[p] = pack2(W[(size_t)k * 8 + c], W[(size_t)(k + 1) * 8 + c]);
    }
    uint4 v = { o[0], o[1], o[2], o[3] };
    *(uint4*)(Wb2 + (size_t)tid * 4) = v;
}

// ---------- layer1+zs fused: h1_tile = relu([h|aggm]@Wb + b1) in LDS, then ------
// z = h1@Wn2 and out_self = h1@Ws2 via 8 more MFMAs. h1 never touches global.
__global__ __launch_bounds__(256) void layer1_mfma_k(const uint* __restrict__ hb,
                                                     const uint* __restrict__ aggm,
                                                     const uint* __restrict__ Wb,
                                                     const uint* __restrict__ Wb2,
                                                     const float* __restrict__ b1,
                                                     float* __restrict__ z,
                                                     float* __restrict__ out, int nd1) {
    __shared__ uint lds[64 * 132];   // 33792 B
    int t = threadIdx.x, lane = t & 63, wid = t >> 6;
    int quad = lane >> 4, l16 = lane & 15;
    int r0 = blockIdx.x * 64;

#pragma unroll
    for (int it = 0; it < 8; ++it) {
        int i = t + it * 256;
        int r = i >> 5, u4 = i & 31;
        const uint* src = (u4 < 16) ? (hb + (size_t)(r0 + r) * 64 + u4 * 4)
                                    : (aggm + (size_t)(r0 + r) * 64 + (u4 - 16) * 4);
        *(uint4*)&lds[r * 132 + u4 * 4] = *(const uint4*)src;
    }

    float bias[4];
#pragma unroll
    for (int i = 0; i < 4; ++i) bias[i] = b1[wid * 64 + i * 16 + l16];
    f32x4 acc[4][4];
#pragma unroll
    for (int mf = 0; mf < 4; ++mf)
#pragma unroll
        for (int i = 0; i < 4; ++i)
            acc[mf][i] = (f32x4){ bias[i], bias[i], bias[i], bias[i] };

    __syncthreads();

#pragma unroll
    for (int ks = 0; ks < 8; ++ks) {
        short8 bfr[4];
#pragma unroll
        for (int i = 0; i < 4; ++i) {
            int nf = wid * 4 + i;
            bfr[i] = *(const short8*)(Wb + (size_t)((ks * 16 + nf) * 64 + lane) * 4);
        }
        short8 afr[4];
#pragma unroll
        for (int mf = 0; mf < 4; ++mf) {
            int r = mf * 16 + l16;
            afr[mf] = *(const short8*)&lds[r * 132 + ks * 16 + quad * 4];
        }
#pragma unroll
        for (int mf = 0; mf < 4; ++mf)
#pragma unroll
            for (int i = 0; i < 4; ++i)
                acc[mf][i] = __builtin_amdgcn_mfma_f32_16x16x32_bf16(afr[mf], bfr[i],
                                                                     acc[mf][i], 0, 0, 0);
    }

    __syncthreads();
    // epilogue: relu -> bf16 h1 tile in LDS (ushort stride 264 == dword 132)
    ushort* st = (ushort*)lds;
#pragma unroll
    for (int mf = 0; mf < 4; ++mf)
#pragma unroll
        for (int i = 0; i < 4; ++i) {
            int col = wid * 64 + i * 16 + l16;
#pragma unroll
            for (int reg = 0; reg < 4; ++reg) {
                int row = mf * 16 + quad * 4 + reg;
                st[row * 264 + col] = f2bf(fmaxf(acc[mf][i][reg], 0.0f));
            }
        }
    __syncthreads();

    // fused zs: wave wid handles local rows wid*16..wid*16+15 (K=256 from LDS)
    f32x4 zacc = (f32x4){ 0.f, 0.f, 0.f, 0.f };
    int rloc = wid * 16 + l16;
#pragma unroll
    for (int ks = 0; ks < 8; ++ks) {
        short8 a = *(const short8*)&lds[rloc * 132 + ks * 16 + quad * 4];
        short8 b = *(const short8*)(Wb2 + (size_t)(ks * 64 + lane) * 4);
        zacc = __builtin_amdgcn_mfma_f32_16x16x32_bf16(a, b, zacc, 0, 0, 0);
    }
#pragma unroll
    for (int reg = 0; reg < 4; ++reg) {
        int r = r0 + wid * 16 + quad * 4 + reg;
        if (l16 < 8) z[(size_t)r * 8 + l16] = zacc[reg];
        else if (r < nd1) out[(size_t)r * 8 + (l16 - 8)] = zacc[reg];
    }
}

// ---------- gz: out += mean-gather(z) + b2 ; 8 threads per dst row ----
__global__ __launch_bounds__(256) void gz_k(const int* __restrict__ csr,
                                            const int* __restrict__ row_start,
                                            const int* __restrict__ cnt,
                                            const float* __restrict__ z,
                                            const float* __restrict__ b2,
                                            float* __restrict__ out, int nrows) {
    int tid = blockIdx.x * 256 + threadIdx.x;
    int d = tid >> 3, c = tid & 7;
    if (d >= nrows) return;
    int beg = row_start[d], n = cnt[d];
    int end = beg + ((n + 3) & ~3);   // 8-padded rows: pads beyond this hit zero row anyway
    float a = 0.f;
    for (int j = beg; j < end; j += 4) {
        int4 s4 = *(const int4*)(csr + j);     // pad slots -> zero z row
        a += z[(size_t)s4.x * 8 + c] + z[(size_t)s4.y * 8 + c]
           + z[(size_t)s4.z * 8 + c] + z[(size_t)s4.w * 8 + c];
    }
    float inv = 1.0f / fmaxf((float)n, 1.0f);
    out[(size_t)d * 8 + c] += a * inv + b2[c];
}

extern "C" void kernel_launch(void* const* d_in, const int* in_sizes, int n_in,
                              void* d_out, int out_size, void* d_ws, size_t ws_size,
                              hipStream_t stream) {
    const float* x    = (const float*)d_in[0];
    const int*   src0 = (const int*)d_in[1];
    const int*   dst0 = (const int*)d_in[2];
    const int*   src1 = (const int*)d_in[3];
    const int*   dst1 = (const int*)d_in[4];
    const float* emb  = (const float*)d_in[7];
    const float* Ws1  = (const float*)d_in[8];
    const float* Wn1  = (const float*)d_in[9];
    const float* b1   = (const float*)d_in[10];
    const float* Ws2  = (const float*)d_in[11];
    const float* Wn2  = (const float*)d_in[12];
    const float* b2   = (const float*)d_in[13];
    int E0 = in_sizes[1];
    int E1 = in_sizes[3];
    int nsrc = in_sizes[0] / 129;   // 400000

    // ---- workspace layout ----
    char* p = (char*)d_ws;
    ushort* h         = (ushort*)p;  p += ((size_t)nsrc + 1) * INF * 2;  // +1 zero row
    uint*   aggm      = (uint*)p;    p += (size_t)ND0 * 64 * 4;          // 51.2 MB
    int*    csr       = (int*)p;     p += ((size_t)E0 + 7 * (size_t)ND0 + 16) * 4;
    int*    cnt       = (int*)p;     p += (size_t)ND0 * 4;
    int*    row_start = (int*)p;     p += (size_t)ND0 * 4;
    int*    bsum      = (int*)p;     p += 256 * 4;
    int*    gcur      = (int*)p;     p += 256 * GSTRIDE * 4;             // 16 KB padded
    uint*   Wb        = (uint*)p;    p += 8192 * 16;
    uint*   Wb2       = (uint*)p;    p += 512 * 16;                      // 8 KB
    float*  z         = (float*)p;   p += ((size_t)ND0 + 1) * 8 * 4;     // +1 zero row
    // pairs overlaid on aggm (dead during CSR build; stream order makes it safe)
    uint*   pairs     = aggm;        // 256*BCAP*4 = 33.5 MB <= 51.2 MB

    int ZR0 = nsrc;   // zero row index in h
    int ZR1 = ND0;    // zero row index in z

    // ---- layer 0/1 ----
    hipMemsetAsync(gcur, 0, 256 * GSTRIDE * 4, stream);
    hipMemsetAsync(h + (size_t)ZR0 * INF, 0, INF * 2, stream);
    gate_k<<<(nsrc * 16 + 255) / 256, 256, 0, stream>>>(x, emb, h, nsrc);
    wconv_k<<<32, 256, 0, stream>>>(Ws1, Wn1, Wb);
    wpack2_k<<<2, 256, 0, stream>>>(Ws2, Wn2, Wb2);
    int nb0 = (ND0 + SCAN_B - 1) / SCAN_B;   // 196
    int ch0 = (E0 + 256 * 16 - 1) / (256 * 16);   // 782 rounds
    binA_k<16><<<ch0, 256, 0, stream>>>(src0, dst0, pairs, gcur, E0);
    binC_k<<<nb0, 1024, 0, stream>>>(pairs, gcur, cnt, ND0);
    scan1_k<<<nb0, 256, 0, stream>>>(cnt, row_start, bsum, ND0);
    scan2_k<<<1, 256, 0, stream>>>(bsum, nb0);
    scan3_k<<<(ND0 + 255) / 256, 256, 0, stream>>>(row_start, bsum, ND0);
    binB_k<<<nb0, 1024, 0, stream>>>(pairs, gcur, row_start, csr, ND0, ZR0);
    gather4_k<<<(ND0 + 3) / 4, 256, 0, stream>>>(csr, row_start, cnt, h, aggm, ND0);
    layer1_mfma_k<<<ND0 / 64, 256, 0, stream>>>((const uint*)h, aggm, Wb, Wb2, b1,
                                                z, (float*)d_out, ND1);

    // ---- layer 2 CSR + neighbor head (z already computed by fused layer1) ----
    hipMemsetAsync(gcur, 0, 256 * GSTRIDE * 4, stream);
    hipMemsetAsync(z + (size_t)ZR1 * 8, 0, 8 * 4, stream);
    int nb1 = (ND1 + SCAN_B - 1) / SCAN_B;   // 98
    int ch1 = (E1 + 256 * 8 - 1) / (256 * 8);    // 782 rounds (chunk 2048)
    binA_k<8><<<ch1, 256, 0, stream>>>(src1, dst1, pairs, gcur, E1);
    binC_k<<<nb1, 1024, 0, stream>>>(pairs, gcur, cnt, ND1);
    scan1_k<<<nb1, 256, 0, stream>>>(cnt, row_start, bsum, ND1);
    scan2_k<<<1, 256, 0, stream>>>(bsum, nb1);
    scan3_k<<<(ND1 + 255) / 256, 256, 0, stream>>>(row_start, bsum, ND1);
    binB_k<<<nb1, 1024, 0, stream>>>(pairs, gcur, row_start, csr, ND1, ZR1);
    gz_k<<<(ND1 * 8 + 255) / 256, 256, 0, stream>>>(csr, row_start, cnt, z, b2,
                                                    (float*)d_out, ND1);
}

// Round 7
// 712.882 us; speedup vs baseline: 1.0694x; 1.0157x over previous
//
#include <hip/hip_runtime.h>

typedef unsigned int uint;
typedef unsigned short ushort;
typedef __attribute__((ext_vector_type(8))) short short8;   // 8 bf16 (4 VGPRs)
typedef __attribute__((ext_vector_type(4))) float f32x4;    // MFMA accumulator
typedef __attribute__((ext_vector_type(2))) float f32x2;    // v_pk_add_f32 pair

// ---------- bf16 helpers (internal storage only; I/O is fp32) ----------
__device__ __forceinline__ float bflo(uint u) { return __uint_as_float(u << 16); }
__device__ __forceinline__ float bfhi(uint u) { return __uint_as_float(u & 0xffff0000u); }
__device__ __forceinline__ ushort f2bf(float f) {
    uint u = __float_as_uint(f);
    u += 0x7fffu + ((u >> 16) & 1u);   // round-to-nearest-even
    return (ushort)(u >> 16);
}
__device__ __forceinline__ uint pack2(float a, float b) {
    return (uint)f2bf(a) | ((uint)f2bf(b) << 16);
}
__device__ __forceinline__ float sigm(float e) { return 1.0f / (1.0f + __expf(-e)); }

#define ND0 200000
#define ND1 100000
#define INF 128
#define HF  256
#define BCAP 32768   // bucket capacity incl. 16-entry flush padding (worst ~29K)
#define GSTRIDE 16   // gcur padded to 64B/line to avoid same-line atomic serialization
#define NBKT 200     // max 1024-dst buckets (196 for ND0, 98 for ND1)
#define CAP_A 48     // per-bucket LDS staging capacity per round (mean ~21, ~6 sigma)
#define SENT 0xFFFFFFFFu   // pad sentinel; real entries max (400000<<10)|1023 < SENT

// ---------- 1) gate: h[n,f] = feat * sigmoid(emb[cell_id]) ; h bf16 ----------
__global__ __launch_bounds__(256) void gate_k(const float* __restrict__ x,
                                              const float* __restrict__ emb,
                                              ushort* __restrict__ h, int nnodes) {
    int tid  = blockIdx.x * 256 + threadIdx.x;
    int node = tid >> 4, tq = tid & 15;
    if (node >= nnodes) return;
    const float* xr = x + (size_t)node * 129;
    int cell = (int)xr[0];
    int f0 = tq * 8;
    const float* er = emb + cell * INF + f0;
    float4 e0 = *(const float4*)er;
    float4 e1 = *(const float4*)(er + 4);
    float v[8];
    __builtin_memcpy(&v[0], xr + 1 + f0, 16);      // 4B-aligned dwordx4
    __builtin_memcpy(&v[4], xr + 5 + f0, 16);
    uint4 o;
    o.x = pack2(v[0] * sigm(e0.x), v[1] * sigm(e0.y));
    o.y = pack2(v[2] * sigm(e0.z), v[3] * sigm(e0.w));
    o.z = pack2(v[4] * sigm(e1.x), v[5] * sigm(e1.y));
    o.w = pack2(v[6] * sigm(e1.z), v[7] * sigm(e1.w));
    *(uint4*)(h + (size_t)node * INF + f0) = o;
}

// ---------- scan2: exclusive scan of per-bucket padded totals (1 block) ----------
__global__ __launch_bounds__(256) void scan2_k(int* __restrict__ bsum, int nb) {
    __shared__ int tmp[256];
    int t = threadIdx.x;
    int s = (t < nb) ? bsum[t] : 0;
    tmp[t] = s; __syncthreads();
    for (int off = 1; off < 256; off <<= 1) {
        int xv = (t >= off) ? tmp[t - off] : 0; __syncthreads();
        tmp[t] += xv; __syncthreads();
    }
    if (t < nb) bsum[t] = tmp[t] - s;   // exclusive
}

// binA: partition edges into 1024-wide dst buckets with LDS write-combining.
// Each block = one round of 256*CPT edges. Edges staged per-bucket in LDS,
// flushed in 16-entry (64B) sentinel-padded granules -> full-line HBM writes.
template <int CPT>
__global__ __launch_bounds__(256) void binA_k(const int* __restrict__ src,
                                              const int* __restrict__ dst,
                                              uint* __restrict__ pairs,
                                              int* __restrict__ gcur, int E) {
    __shared__ int  lcur[NBKT];
    __shared__ uint stage[NBKT][CAP_A];
    int t = threadIdx.x;
    int c0 = blockIdx.x * (256 * CPT);
    int n = min(256 * CPT, E - c0);
    for (int i = t; i < NBKT; i += 256) lcur[i] = 0;
    __syncthreads();

    int i0 = t * CPT;
    if (i0 + CPT <= n) {
#pragma unroll
        for (int v = 0; v < CPT / 4; ++v) {
            int4 d4 = *(const int4*)(dst + c0 + i0 + v * 4);
            int4 s4 = *(const int4*)(src + c0 + i0 + v * 4);
            int dv[4] = { d4.x, d4.y, d4.z, d4.w };
            int sv[4] = { s4.x, s4.y, s4.z, s4.w };
#pragma unroll
            for (int q = 0; q < 4; ++q) {
                int d = dv[q];
                int b = d >> 10;
                uint e = ((uint)sv[q] << 10) | (uint)(d & 1023);
                int r = atomicAdd(&lcur[b], 1);
                if (r < CAP_A) stage[b][r] = e;
                else {   // staging overflow (rare): direct global slot
                    int p = atomicAdd(&gcur[b * GSTRIDE], 1);
                    pairs[(size_t)b * BCAP + p] = e;
                }
            }
        }
    } else {
        for (int q = 0; q < CPT; ++q) {
            int i = i0 + q;
            if (i >= n) break;
            int d = dst[c0 + i];
            int b = d >> 10;
            uint e = ((uint)src[c0 + i] << 10) | (uint)(d & 1023);
            int r = atomicAdd(&lcur[b], 1);
            if (r < CAP_A) stage[b][r] = e;
            else {
                int p = atomicAdd(&gcur[b * GSTRIDE], 1);
                pairs[(size_t)b * BCAP + p] = e;
            }
        }
    }
    __syncthreads();

    // flush: one wave per bucket, 16-entry-padded reservation -> 64B-aligned lines
    int wid = t >> 6, lane = t & 63;
    for (int b = wid; b < NBKT; b += 4) {
        int cnt = min(lcur[b], CAP_A);
        if (cnt == 0) continue;
        int padded = (cnt + 15) & ~15;            // 16/32/48 <= 64 lanes
        int base;
        if (lane == 0) base = atomicAdd(&gcur[b * GSTRIDE], padded);
        base = __shfl(base, 0);
        if (lane < padded)
            pairs[(size_t)b * BCAP + base + lane] = (lane < cnt) ? stage[b][lane] : SENT;
    }
}

// binC: per-bucket histogram + fused block-local padded prefix scan.
// Emits cnt (real counts), row_start (block-LOCAL 8-padded offsets),
// bsum[b] (bucket padded total). Replaces the old scan1/scan3 passes.
__global__ __launch_bounds__(1024) void binC_k(const uint* __restrict__ pairs,
                                               const int* __restrict__ gcur,
                                               int* __restrict__ cnt,
                                               int* __restrict__ row_start,
                                               int* __restrict__ bsum, int nd) {
    __shared__ int hh[1024];
    __shared__ int sc[1024];
    int b = blockIdx.x, t = threadIdx.x;
    hh[t] = 0;
    __syncthreads();
    int ne = gcur[b * GSTRIDE];
    const uint* bp = pairs + (size_t)b * BCAP;
    for (int i = t; i < ne; i += 1024) {
        uint e = bp[i];
        if (e != SENT) atomicAdd(&hh[e & 1023], 1);
    }
    __syncthreads();
    int hv = hh[t];
    int v  = (hv + 7) & ~7;         // 8-padded row length
    sc[t] = v;
    __syncthreads();
    for (int off = 1; off < 1024; off <<= 1) {
        int xv = (t >= off) ? sc[t - off] : 0; __syncthreads();
        sc[t] += xv; __syncthreads();
    }
    int d = (b << 10) + t;
    if (d < nd) {
        cnt[d]       = hv;
        row_start[d] = sc[t] - v;   // exclusive, block-local
    }
    if (t == 1023) bsum[b] = sc[1023];
}

// binB: one block per bucket, LDS per-dst cursors, L2-local csr writes + pad fill.
// row_start is block-local; global base comes from bsum[b]. Zeros gcur[b] after
// use so the next layer's binA needs no memset.
__global__ __launch_bounds__(1024) void binB_k(const uint* __restrict__ pairs,
                                               int* __restrict__ gcur,
                                               const int* __restrict__ row_start,
                                               const int* __restrict__ bsum,
                                               int* __restrict__ csr, int nd, int zrow) {
    __shared__ int cur[1024];
    int b = blockIdx.x, t = threadIdx.x;
    int dbase = b << 10;
    int gbase = bsum[b];
    cur[t] = (dbase + t < nd) ? gbase + row_start[dbase + t] : 0;
    __syncthreads();
    int ne = gcur[b * GSTRIDE];
    const uint* bp = pairs + (size_t)b * BCAP;
    for (int i = t; i < ne; i += 1024) {
        uint e = bp[i];
        if (e == SENT) continue;
        int p = atomicAdd(&cur[e & 1023], 1);
        csr[p] = (int)(e >> 10);
    }
    __syncthreads();
    // pad each row to a multiple of 8 with the zero-row index (fused fill)
    if (dbase + t < nd) {
        int pe = cur[t];                       // start + cnt
        int st = gbase + row_start[dbase + t];
        int pad = (-(pe - st)) & 7;
        for (int q = 0; q < pad; ++q) csr[pe + q] = zrow;
    }
    if (t == 0) gcur[b * GSTRIDE] = 0;         // reset cursor for next layer
}

// ---------- gather4: wave per dst row; 16 lanes per src row (uint4/lane);
// unroll-2 over 8-padded rows (2 KB in flight/wave); f32x2 -> v_pk_add_f32. ----
__global__ __launch_bounds__(256) void gather4_k(const int* __restrict__ csr,
                                                 const int* __restrict__ row_start,
                                                 const int* __restrict__ bsum,
                                                 const int* __restrict__ cnt,
                                                 const ushort* __restrict__ hsrc,
                                                 uint* __restrict__ aggm, int nrows) {
    int w    = (blockIdx.x * blockDim.x + threadIdx.x) >> 6;
    int lane = threadIdx.x & 63;
    if (w >= nrows) return;
    int e  = lane >> 4;        // edge slot 0..3 within each group of 4
    int fo = (lane & 15) * 4;  // dword offset within the 64-dword row
    int beg = bsum[w >> 10] + row_start[w], c = cnt[w];
    int end = beg + ((c + 7) & ~7);
    const uint* hb = (const uint*)hsrc;
    f32x2 A[4] = {{0.f,0.f},{0.f,0.f},{0.f,0.f},{0.f,0.f}};
    f32x2 B[4] = {{0.f,0.f},{0.f,0.f},{0.f,0.f},{0.f,0.f}};
    if (beg < end) {
        int r0 = csr[beg + e];
        int r1 = csr[beg + 4 + e];
        for (int j = beg; j < end; j += 8) {
            int n0 = 0, n1 = 0;
            if (j + 8 < end) {
                n0 = csr[j + 8 + e];
                n1 = csr[j + 12 + e];
            }
            uint4 h0 = *(const uint4*)(hb + (size_t)r0 * 64 + fo);
            uint4 h1 = *(const uint4*)(hb + (size_t)r1 * 64 + fo);
            A[0] += (f32x2){ bflo(h0.x), bfhi(h0.x) };
            A[1] += (f32x2){ bflo(h0.y), bfhi(h0.y) };
            A[2] += (f32x2){ bflo(h0.z), bfhi(h0.z) };
            A[3] += (f32x2){ bflo(h0.w), bfhi(h0.w) };
            B[0] += (f32x2){ bflo(h1.x), bfhi(h1.x) };
            B[1] += (f32x2){ bflo(h1.y), bfhi(h1.y) };
            B[2] += (f32x2){ bflo(h1.z), bfhi(h1.z) };
            B[3] += (f32x2){ bflo(h1.w), bfhi(h1.w) };
            r0 = n0; r1 = n1;
        }
    }
#pragma unroll
    for (int i = 0; i < 4; ++i) A[i] += B[i];
    // cross-group reduce: 4 lane-groups hold partial sums of the same features
#pragma unroll
    for (int i = 0; i < 4; ++i) {
        A[i].x += __shfl_xor(A[i].x, 16);
        A[i].y += __shfl_xor(A[i].y, 16);
        A[i].x += __shfl_xor(A[i].x, 32);
        A[i].y += __shfl_xor(A[i].y, 32);
    }
    if (lane < 16) {
        float inv = 1.0f / fmaxf((float)c, 1.0f);
        uint4 o;
        o.x = pack2(A[0].x * inv, A[0].y * inv);
        o.y = pack2(A[1].x * inv, A[1].y * inv);
        o.z = pack2(A[2].x * inv, A[2].y * inv);
        o.w = pack2(A[3].x * inv, A[3].y * inv);
        *(uint4*)(aggm + (size_t)w * 64 + fo) = o;
    }
}

// ---------- W pack: [Ws1;Wn1] (256x256 f32) -> B-fragment-major bf16 ----------
__global__ __launch_bounds__(256) void wconv_k(const float* __restrict__ Ws,
                                               const float* __restrict__ Wn,
                                               uint* __restrict__ Wb) {
    int tid  = blockIdx.x * 256 + threadIdx.x;   // 8192 threads
    int lane = tid & 63, nf = (tid >> 6) & 15, ks = tid >> 10;
    int n  = nf * 16 + (lane & 15);
    int k0 = ks * 32 + ((lane >> 4) << 3);
    uint o[4];
#pragma unroll
    for (int p = 0; p < 4; ++p) {
        int k = k0 + 2 * p;
        float a = (k < 128)     ? Ws[(size_t)k * HF + n]       : Wn[(size_t)(k - 128) * HF + n];
        float b = (k + 1 < 128) ? Ws[(size_t)(k + 1) * HF + n] : Wn[(size_t)(k - 127) * HF + n];
        o[p] = pack2(a, b);
    }
    uint4 v = { o[0], o[1], o[2], o[3] };
    *(uint4*)(Wb + (size_t)tid * 4) = v;
}

// ---------- W pack 2: B2 = [Wn2 (cols 0-7) | Ws2 (cols 8-15)], 256x16 bf16 -----
__global__ __launch_bounds__(256) void wpack2_k(const float* __restrict__ Ws2,
                                                const float* __restrict__ Wn2,
                                                uint* __restrict__ Wb2) {
    int tid = blockIdx.x * 256 + threadIdx.x;   // 512 threads
    if (tid >= 512) return;
    int lane = tid & 63, ks = tid >> 6;
    int n  = lane & 15;
    int k0 = ks * 32 + ((lane >> 4) << 3);
    const float* W = (n < 8) ? Wn2 : Ws2;
    int c = n & 7;
    uint o[4];
#pragma unroll
    for (int p = 0; p < 4; ++p) {
        int k = k0 + 2 * p;
        o[p] = pack2(W[(size_t)k * 8 + c], W[(size_t)(k + 1) * 8 + c]);
    }
    uint4 v = { o[0], o[1], o[2], o[3] };
    *(uint4*)(Wb2 + (size_t)tid * 4) = v;
}

// ---------- layer1+zs fused: h1_tile = relu([h|aggm]@Wb + b1) in LDS, then ------
// z = h1@Wn2 and out_self = h1@Ws2 via 8 more MFMAs. h1 never touches global.
__global__ __launch_bounds__(256) void layer1_mfma_k(const uint* __restrict__ hb,
                                                     const uint* __restrict__ aggm,
                                                     const uint* __restrict__ Wb,
                                                     const uint* __restrict__ Wb2,
                                                     const float* __restrict__ b1,
                                                     float* __restrict__ z,
                                                     float* __restrict__ out, int nd1) {
    __shared__ uint lds[64 * 132];   // 33792 B
    int t = threadIdx.x, lane = t & 63, wid = t >> 6;
    int quad = lane >> 4, l16 = lane & 15;
    int r0 = blockIdx.x * 64;

#pragma unroll
    for (int it = 0; it < 8; ++it) {
        int i = t + it * 256;
        int r = i >> 5, u4 = i & 31;
        const uint* src = (u4 < 16) ? (hb + (size_t)(r0 + r) * 64 + u4 * 4)
                                    : (aggm + (size_t)(r0 + r) * 64 + (u4 - 16) * 4);
        *(uint4*)&lds[r * 132 + u4 * 4] = *(const uint4*)src;
    }

    float bias[4];
#pragma unroll
    for (int i = 0; i < 4; ++i) bias[i] = b1[wid * 64 + i * 16 + l16];
    f32x4 acc[4][4];
#pragma unroll
    for (int mf = 0; mf < 4; ++mf)
#pragma unroll
        for (int i = 0; i < 4; ++i)
            acc[mf][i] = (f32x4){ bias[i], bias[i], bias[i], bias[i] };

    __syncthreads();

#pragma unroll
    for (int ks = 0; ks < 8; ++ks) {
        short8 bfr[4];
#pragma unroll
        for (int i = 0; i < 4; ++i) {
            int nf = wid * 4 + i;
            bfr[i] = *(const short8*)(Wb + (size_t)((ks * 16 + nf) * 64 + lane) * 4);
        }
        short8 afr[4];
#pragma unroll
        for (int mf = 0; mf < 4; ++mf) {
            int r = mf * 16 + l16;
            afr[mf] = *(const short8*)&lds[r * 132 + ks * 16 + quad * 4];
        }
#pragma unroll
        for (int mf = 0; mf < 4; ++mf)
#pragma unroll
            for (int i = 0; i < 4; ++i)
                acc[mf][i] = __builtin_amdgcn_mfma_f32_16x16x32_bf16(afr[mf], bfr[i],
                                                                     acc[mf][i], 0, 0, 0);
    }

    __syncthreads();
    // epilogue: relu -> bf16 h1 tile in LDS (ushort stride 264 == dword 132)
    ushort* st = (ushort*)lds;
#pragma unroll
    for (int mf = 0; mf < 4; ++mf)
#pragma unroll
        for (int i = 0; i < 4; ++i) {
            int col = wid * 64 + i * 16 + l16;
#pragma unroll
            for (int reg = 0; reg < 4; ++reg) {
                int row = mf * 16 + quad * 4 + reg;
                st[row * 264 + col] = f2bf(fmaxf(acc[mf][i][reg], 0.0f));
            }
        }
    __syncthreads();

    // fused zs: wave wid handles local rows wid*16..wid*16+15 (K=256 from LDS)
    f32x4 zacc = (f32x4){ 0.f, 0.f, 0.f, 0.f };
    int rloc = wid * 16 + l16;
#pragma unroll
    for (int ks = 0; ks < 8; ++ks) {
        short8 a = *(const short8*)&lds[rloc * 132 + ks * 16 + quad * 4];
        short8 b = *(const short8*)(Wb2 + (size_t)(ks * 64 + lane) * 4);
        zacc = __builtin_amdgcn_mfma_f32_16x16x32_bf16(a, b, zacc, 0, 0, 0);
    }
#pragma unroll
    for (int reg = 0; reg < 4; ++reg) {
        int r = r0 + wid * 16 + quad * 4 + reg;
        if (l16 < 8) z[(size_t)r * 8 + l16] = zacc[reg];
        else if (r < nd1) out[(size_t)r * 8 + (l16 - 8)] = zacc[reg];
    }
}

// ---------- gz: out += mean-gather(z) + b2 ; 8 threads per dst row ----
__global__ __launch_bounds__(256) void gz_k(const int* __restrict__ csr,
                                            const int* __restrict__ row_start,
                                            const int* __restrict__ bsum,
                                            const int* __restrict__ cnt,
                                            const float* __restrict__ z,
                                            const float* __restrict__ b2,
                                            float* __restrict__ out, int nrows) {
    int tid = blockIdx.x * 256 + threadIdx.x;
    int d = tid >> 3, c = tid & 7;
    if (d >= nrows) return;
    int beg = bsum[d >> 10] + row_start[d], n = cnt[d];
    int end = beg + ((n + 3) & ~3);   // 8-padded rows: pads beyond this hit zero row anyway
    float a = 0.f;
    for (int j = beg; j < end; j += 4) {
        int4 s4 = *(const int4*)(csr + j);     // pad slots -> zero z row
        a += z[(size_t)s4.x * 8 + c] + z[(size_t)s4.y * 8 + c]
           + z[(size_t)s4.z * 8 + c] + z[(size_t)s4.w * 8 + c];
    }
    float inv = 1.0f / fmaxf((float)n, 1.0f);
    out[(size_t)d * 8 + c] += a * inv + b2[c];
}

extern "C" void kernel_launch(void* const* d_in, const int* in_sizes, int n_in,
                              void* d_out, int out_size, void* d_ws, size_t ws_size,
                              hipStream_t stream) {
    const float* x    = (const float*)d_in[0];
    const int*   src0 = (const int*)d_in[1];
    const int*   dst0 = (const int*)d_in[2];
    const int*   src1 = (const int*)d_in[3];
    const int*   dst1 = (const int*)d_in[4];
    const float* emb  = (const float*)d_in[7];
    const float* Ws1  = (const float*)d_in[8];
    const float* Wn1  = (const float*)d_in[9];
    const float* b1   = (const float*)d_in[10];
    const float* Ws2  = (const float*)d_in[11];
    const float* Wn2  = (const float*)d_in[12];
    const float* b2   = (const float*)d_in[13];
    int E0 = in_sizes[1];
    int E1 = in_sizes[3];
    int nsrc = in_sizes[0] / 129;   // 400000

    // ---- workspace layout ----
    char* p = (char*)d_ws;
    ushort* h         = (ushort*)p;  p += ((size_t)nsrc + 1) * INF * 2;  // +1 zero row
    uint*   aggm      = (uint*)p;    p += (size_t)ND0 * 64 * 4;          // 51.2 MB
    int*    csr       = (int*)p;     p += ((size_t)E0 + 7 * (size_t)ND0 + 16) * 4;
    int*    cnt       = (int*)p;     p += (size_t)ND0 * 4;
    int*    row_start = (int*)p;     p += (size_t)ND0 * 4;
    int*    bsum      = (int*)p;     p += 256 * 4;
    int*    gcur      = (int*)p;     p += 256 * GSTRIDE * 4;             // 16 KB padded
    uint*   Wb        = (uint*)p;    p += 8192 * 16;
    uint*   Wb2       = (uint*)p;    p += 512 * 16;                      // 8 KB
    float*  z         = (float*)p;   p += ((size_t)ND0 + 1) * 8 * 4;     // +1 zero row
    // pairs overlaid on aggm (dead during CSR build; stream order makes it safe)
    uint*   pairs     = aggm;        // 256*BCAP*4 = 33.5 MB <= 51.2 MB

    int ZR0 = nsrc;   // zero row index in h
    int ZR1 = ND0;    // zero row index in z

    // ---- layer 0/1 ----
    hipMemsetAsync(gcur, 0, 256 * GSTRIDE * 4, stream);
    hipMemsetAsync(h + (size_t)ZR0 * INF, 0, INF * 2, stream);
    gate_k<<<(nsrc * 16 + 255) / 256, 256, 0, stream>>>(x, emb, h, nsrc);
    wconv_k<<<32, 256, 0, stream>>>(Ws1, Wn1, Wb);
    wpack2_k<<<2, 256, 0, stream>>>(Ws2, Wn2, Wb2);
    int nb0 = (ND0 + 1023) / 1024;   // 196
    int ch0 = (E0 + 256 * 16 - 1) / (256 * 16);   // 782 rounds
    binA_k<16><<<ch0, 256, 0, stream>>>(src0, dst0, pairs, gcur, E0);
    binC_k<<<nb0, 1024, 0, stream>>>(pairs, gcur, cnt, row_start, bsum, ND0);
    scan2_k<<<1, 256, 0, stream>>>(bsum, nb0);
    binB_k<<<nb0, 1024, 0, stream>>>(pairs, gcur, row_start, bsum, csr, ND0, ZR0);
    gather4_k<<<(ND0 + 3) / 4, 256, 0, stream>>>(csr, row_start, bsum, cnt, h, aggm, ND0);
    layer1_mfma_k<<<ND0 / 64, 256, 0, stream>>>((const uint*)h, aggm, Wb, Wb2, b1,
                                                z, (float*)d_out, ND1);

    // ---- layer 2 CSR + neighbor head (z already computed by fused layer1) ----
    // gcur already zeroed by layer-1 binB (buckets 0..195 cover 0..97)
    hipMemsetAsync(z + (size_t)ZR1 * 8, 0, 8 * 4, stream);
    int nb1 = (ND1 + 1023) / 1024;   // 98
    int ch1 = (E1 + 256 * 8 - 1) / (256 * 8);    // 782 rounds (chunk 2048)
    binA_k<8><<<ch1, 256, 0, stream>>>(src1, dst1, pairs, gcur, E1);
    binC_k<<<nb1, 1024, 0, stream>>>(pairs, gcur, cnt, row_start, bsum, ND1);
    scan2_k<<<1, 256, 0, stream>>>(bsum, nb1);
    binB_k<<<nb1, 1024, 0, stream>>>(pairs, gcur, row_start, bsum, csr, ND1, ZR1);
    gz_k<<<(ND1 * 8 + 255) / 256, 256, 0, stream>>>(csr, row_start, bsum, cnt, z, b2,
                                                    (float*)d_out, ND1);
}